// Round 1
// baseline (546.024 us; speedup 1.0000x reference)
//
#include <hip/hip_runtime.h>

typedef __bf16 bf16_t;
typedef bf16_t bf16x8 __attribute__((ext_vector_type(8)));
typedef float f32x4 __attribute__((ext_vector_type(4)));

union U8 { bf16x8 v; ushort4 h[2]; };

__device__ __forceinline__ unsigned short f2bf(float f){
  unsigned int u = __builtin_bit_cast(unsigned int, f);
  u = (u + 0x7FFFu + ((u >> 16) & 1u)) >> 16;
  return (unsigned short)u;
}
__device__ __forceinline__ ushort4 pack4(f32x4 v){
  ushort4 r; r.x=f2bf(v[0]); r.y=f2bf(v[1]); r.z=f2bf(v[2]); r.w=f2bf(v[3]); return r;
}

#define MFMA16(a,b,c) __builtin_amdgcn_mfma_f32_16x16x32_bf16((a),(b),(c),0,0,0)

constexpr int BN = 2;      // batch
constexpr int CC = 256;    // channels
constexpr int S  = 4096;   // 64*64 spatial
constexpr int HH = 4;      // heads
constexpr int DD = 64;     // head dim

// ws layout (all bf16 stored as unsigned short)
constexpr size_t OFF_WQ = 0;
constexpr size_t OFF_WK = 65536;
constexpr size_t OFF_WV = 131072;
constexpr size_t OFF_WO = 196608;
constexpr size_t OFF_NY = 262144;                      // normed y: [b][p][c]
constexpr size_t OFF_NX = OFF_NY + (size_t)BN*S*CC;    // normed x: [b][p][c]
constexpr size_t OFF_Q  = OFF_NX + (size_t)BN*S*CC;    // [b][h][p][d]  (pre-scaled by 1/8)
constexpr size_t OFF_K  = OFF_Q  + (size_t)BN*S*CC;    // [b][h][p][d]
constexpr size_t OFF_V  = OFF_K  + (size_t)BN*S*CC;    // [b][c][p]  (channel-major = V^T)
constexpr size_t OFF_AO = OFF_V  + (size_t)BN*S*CC;    // attn out: [b][p][c]
// total = 12,845,056 ushort = 25,690,112 bytes

// ---------------- weight fp32 -> bf16 ----------------
__global__ __launch_bounds__(256) void convert_w(const float* __restrict__ wq, const float* __restrict__ wk,
    const float* __restrict__ wv, const float* __restrict__ wo, unsigned short* __restrict__ ws)
{
  const int idx = blockIdx.x*256 + threadIdx.x;      // 65536 threads, 4 floats each
  const int m = idx >> 14;
  const int off = (idx & 16383) << 2;
  const float* src = (m==0) ? wq : (m==1) ? wk : (m==2) ? wv : wo;
  float4 v = *(const float4*)(src + off);
  ushort4 r; r.x=f2bf(v.x); r.y=f2bf(v.y); r.z=f2bf(v.z); r.w=f2bf(v.w);
  *(ushort4*)(ws + (size_t)m*65536 + off) = r;
}

// ---------------- GroupNorm (32 groups of 8 ch), writes [p][c] bf16 ----------------
__global__ __launch_bounds__(256) void groupnorm_k(const float* __restrict__ x, const float* __restrict__ y,
    const float* __restrict__ g1, const float* __restrict__ b1,
    const float* __restrict__ g2, const float* __restrict__ b2,
    unsigned short* __restrict__ ws)
{
  const int tid = threadIdx.x;
  const int bid = blockIdx.x;
  const int tsel = bid >> 6;          // 0: x -> NX, 1: y -> NY
  const int rem  = bid & 63;
  const int b = rem >> 5, g = rem & 31;
  const float* in = (tsel ? y : x) + ((size_t)b*CC + g*8)*S;
  unsigned short* outp = ws + (tsel ? OFF_NY : OFF_NX) + (size_t)b*S*CC + g*8;
  const float* gamma = (tsel ? g2 : g1) + g*8;
  const float* beta  = (tsel ? b2 : b1) + g*8;

  float s = 0.f, ss = 0.f;
  #pragma unroll
  for (int ci = 0; ci < 8; ci++){
    const float4* row = (const float4*)(in + (size_t)ci*S);
    #pragma unroll
    for (int i = 0; i < 4; i++){
      float4 v = row[tid + i*256];
      s  += v.x + v.y + v.z + v.w;
      ss += v.x*v.x + v.y*v.y + v.z*v.z + v.w*v.w;
    }
  }
  #pragma unroll
  for (int off = 1; off < 64; off <<= 1){
    s  += __shfl_xor(s,  off);
    ss += __shfl_xor(ss, off);
  }
  __shared__ float red[8];
  __shared__ float mv[2];
  const int wave = tid >> 6, lane = tid & 63;
  if (lane == 0){ red[wave] = s; red[4+wave] = ss; }
  __syncthreads();
  if (tid == 0){
    float S1 = red[0]+red[1]+red[2]+red[3];
    float S2 = red[4]+red[5]+red[6]+red[7];
    const float invn = 1.0f/32768.0f;
    float mean = S1*invn;
    float var  = S2*invn - mean*mean;
    mv[0] = mean; mv[1] = rsqrtf(var + 1e-6f);
  }
  __syncthreads();
  const float mean = mv[0], rstd = mv[1];
  float sc[8], sh[8];
  #pragma unroll
  for (int ci = 0; ci < 8; ci++){ sc[ci] = rstd*gamma[ci]; sh[ci] = beta[ci] - mean*sc[ci]; }
  for (int i = 0; i < 16; i++){
    const int p = tid + i*256;
    ushort4 o0, o1;
    o0.x = f2bf(in[0*S+p]*sc[0]+sh[0]);
    o0.y = f2bf(in[1*S+p]*sc[1]+sh[1]);
    o0.z = f2bf(in[2*S+p]*sc[2]+sh[2]);
    o0.w = f2bf(in[3*S+p]*sc[3]+sh[3]);
    o1.x = f2bf(in[4*S+p]*sc[4]+sh[4]);
    o1.y = f2bf(in[5*S+p]*sc[5]+sh[5]);
    o1.z = f2bf(in[6*S+p]*sc[6]+sh[6]);
    o1.w = f2bf(in[7*S+p]*sc[7]+sh[7]);
    *(ushort4*)(outp + (size_t)p*CC)     = o0;
    *(ushort4*)(outp + (size_t)p*CC + 4) = o1;
  }
}

// ---------------- Q/K/V projection GEMMs ----------------
// which 0: Q = Wq x normY  -> [b][h][p][d], scaled by 0.125
// which 1: K = Wk x normX  -> [b][h][p][d]
// which 2: V = (normX x Wv^T)^T -> [b][c][p]  (computed transposed: D[p][o])
__global__ __launch_bounds__(256) void qkv_gemm(unsigned short* __restrict__ ws,
    const float* __restrict__ bq, const float* __restrict__ bk, const float* __restrict__ bv)
{
  const int tid = threadIdx.x;
  const int lane = tid & 63, wave = tid >> 6;
  const int lq = lane & 15, lg = lane >> 4;
  const int bid = blockIdx.x;
  const int inst = bid >> 6, tile = bid & 63;   // 6 instances x 64 tiles
  const int which = inst % 3, b = inst / 3;
  int mblk, nblk;
  if (which == 2) { mblk = tile & 31; nblk = tile >> 5; }   // M=4096(p), N=256(o)
  else            { mblk = tile >> 5; nblk = tile & 31; }   // M=256(o),  N=4096(p)
  const int mbase = mblk*128 + (wave>>1)*64;
  const int nbase = nblk*128 + (wave&1)*64;

  const unsigned short* Amat;
  const unsigned short* Bmat;
  if (which == 0)      { Amat = ws + OFF_WQ;                     Bmat = ws + OFF_NY + (size_t)b*S*CC; }
  else if (which == 1) { Amat = ws + OFF_WK;                     Bmat = ws + OFF_NX + (size_t)b*S*CC; }
  else                 { Amat = ws + OFF_NX + (size_t)b*S*CC;    Bmat = ws + OFF_WV; }

  f32x4 acc[4][4];
  #pragma unroll
  for (int i = 0; i < 4; i++)
    #pragma unroll
    for (int j = 0; j < 4; j++)
      acc[i][j] = (f32x4){0.f,0.f,0.f,0.f};

  const unsigned short* Arow = Amat + (size_t)(mbase + lq)*CC;
  const unsigned short* Brow = Bmat + (size_t)(nbase + lq)*CC;

  for (int ks = 0; ks < CC; ks += 32) {
    U8 af[4], bfr[4];
    #pragma unroll
    for (int mt = 0; mt < 4; mt++){
      const unsigned short* p = Arow + (size_t)mt*16*CC + ks + lg*4;
      af[mt].h[0] = *(const ushort4*)p;
      af[mt].h[1] = *(const ushort4*)(p + 16);
    }
    #pragma unroll
    for (int nt = 0; nt < 4; nt++){
      const unsigned short* p = Brow + (size_t)nt*16*CC + ks + lg*4;
      bfr[nt].h[0] = *(const ushort4*)p;
      bfr[nt].h[1] = *(const ushort4*)(p + 16);
    }
    #pragma unroll
    for (int mt = 0; mt < 4; mt++)
      #pragma unroll
      for (int nt = 0; nt < 4; nt++)
        acc[mt][nt] = MFMA16(af[mt].v, bfr[nt].v, acc[mt][nt]);
  }

  if (which < 2) {
    const float* bias = (which==0) ? bq : bk;
    const float scl = (which==0) ? 0.125f : 1.0f;
    unsigned short* Outp = ws + (which==0 ? OFF_Q : OFF_K) + (size_t)b*HH*S*DD;
    #pragma unroll
    for (int mt = 0; mt < 4; mt++){
      const int o = mbase + mt*16 + lg*4;
      const float4 bb = *(const float4*)(bias + o);
      const int h = o >> 6, db = o & 63;
      #pragma unroll
      for (int nt = 0; nt < 4; nt++){
        const int p = nbase + nt*16 + lq;
        f32x4 v = acc[mt][nt];
        ushort4 r;
        r.x = f2bf((v[0]+bb.x)*scl); r.y = f2bf((v[1]+bb.y)*scl);
        r.z = f2bf((v[2]+bb.z)*scl); r.w = f2bf((v[3]+bb.w)*scl);
        *(ushort4*)(Outp + ((size_t)h*S + p)*DD + db) = r;
      }
    }
  } else {
    unsigned short* Outp = ws + OFF_V + (size_t)b*CC*S;
    #pragma unroll
    for (int nt = 0; nt < 4; nt++){
      const int o = nbase + nt*16 + lq;
      const float bb = bv[o];
      #pragma unroll
      for (int mt = 0; mt < 4; mt++){
        const int p = mbase + mt*16 + lg*4;
        f32x4 v = acc[mt][nt];
        ushort4 r;
        r.x = f2bf(v[0]+bb); r.y = f2bf(v[1]+bb);
        r.z = f2bf(v[2]+bb); r.w = f2bf(v[3]+bb);
        *(ushort4*)(Outp + (size_t)o*S + p) = r;
      }
    }
  }
}

// ---------------- flash attention (swapped QK^T), BQ=64 per block ----------------
__global__ __launch_bounds__(256) void attn_k(unsigned short* __restrict__ ws)
{
  const int tid = threadIdx.x;
  const int lane = tid & 63, wave = tid >> 6;
  const int lq = lane & 15, lg = lane >> 4;
  const int bid = blockIdx.x;
  const int bh = bid >> 6;                  // 8 (b,h) x 64 q-blocks
  const int qblk = bid & 63;
  const int b = bh >> 2, h = bh & 3;
  const unsigned short* Qp = ws + OFF_Q + (size_t)bh*S*DD;
  const unsigned short* Kp = ws + OFF_K + (size_t)bh*S*DD;
  const unsigned short* Vp = ws + OFF_V + ((size_t)b*CC + h*DD)*S;
  unsigned short* AOp = ws + OFF_AO + (size_t)b*S*CC;
  const int q = qblk*64 + wave*16 + lq;     // this lane's q column

  U8 qf[2];   // B-frag of Q^T: [d][q], d-halves 0..31 / 32..63
  {
    const unsigned short* p = Qp + (size_t)q*DD + lg*4;
    qf[0].h[0] = *(const ushort4*)p;        qf[0].h[1] = *(const ushort4*)(p+16);
    qf[1].h[0] = *(const ushort4*)(p+32);   qf[1].h[1] = *(const ushort4*)(p+48);
  }
  f32x4 acc[4];
  #pragma unroll
  for (int i = 0; i < 4; i++) acc[i] = (f32x4){0.f,0.f,0.f,0.f};
  float mrun = -1e30f, lrun = 0.f;

  for (int t0 = 0; t0 < S; t0 += 64) {
    f32x4 st[4];
    #pragma unroll
    for (int mt = 0; mt < 4; mt++){
      U8 k0, k1;
      const unsigned short* p = Kp + (size_t)(t0 + mt*16 + lq)*DD + lg*4;
      k0.h[0] = *(const ushort4*)p;      k0.h[1] = *(const ushort4*)(p+16);
      k1.h[0] = *(const ushort4*)(p+32); k1.h[1] = *(const ushort4*)(p+48);
      f32x4 z = (f32x4){0.f,0.f,0.f,0.f};
      z = MFMA16(k0.v, qf[0].v, z);
      z = MFMA16(k1.v, qf[1].v, z);
      st[mt] = z;   // S^T[t0+mt*16+lg*4+r][q]
    }
    // online softmax over t for this lane's q
    float tm = st[0][0];
    #pragma unroll
    for (int mt = 0; mt < 4; mt++)
      #pragma unroll
      for (int r = 0; r < 4; r++)
        tm = fmaxf(tm, st[mt][r]);
    tm = fmaxf(tm, __shfl_xor(tm, 16));
    tm = fmaxf(tm, __shfl_xor(tm, 32));
    const float mnew = fmaxf(mrun, tm);
    float ts = 0.f;
    #pragma unroll
    for (int mt = 0; mt < 4; mt++)
      #pragma unroll
      for (int r = 0; r < 4; r++){
        float e = __expf(st[mt][r] - mnew);
        st[mt][r] = e;
        ts += e;
      }
    ts += __shfl_xor(ts, 16);
    ts += __shfl_xor(ts, 32);
    const float c = __expf(mrun - mnew);
    lrun = lrun*c + ts;
    mrun = mnew;
    // P^T in C-layout == PV B-fragment, zero data movement
    U8 pf0, pf1;
    pf0.h[0] = pack4(st[0]); pf0.h[1] = pack4(st[1]);   // t 0..31
    pf1.h[0] = pack4(st[2]); pf1.h[1] = pack4(st[3]);   // t 32..63
    #pragma unroll
    for (int dt = 0; dt < 4; dt++){
      #pragma unroll
      for (int r = 0; r < 4; r++) acc[dt][r] *= c;
      U8 v0, v1;
      const unsigned short* p = Vp + (size_t)(dt*16 + lq)*S + t0 + lg*4;
      v0.h[0] = *(const ushort4*)p;      v0.h[1] = *(const ushort4*)(p+16);
      v1.h[0] = *(const ushort4*)(p+32); v1.h[1] = *(const ushort4*)(p+48);
      acc[dt] = MFMA16(v0.v, pf0.v, acc[dt]);
      acc[dt] = MFMA16(v1.v, pf1.v, acc[dt]);
    }
  }
  const float inv = 1.0f / lrun;
  #pragma unroll
  for (int dt = 0; dt < 4; dt++){
    f32x4 v;
    #pragma unroll
    for (int r = 0; r < 4; r++) v[r] = acc[dt][r] * inv;
    *(ushort4*)(AOp + (size_t)q*CC + h*DD + dt*16 + lg*4) = pack4(v);
  }
}

// ---------------- output projection + residual ----------------
// D[p][o] = AO[p][:] . wo[o][:] ; out = D + bo + x
__global__ __launch_bounds__(256) void outproj_k(const unsigned short* __restrict__ ws,
    const float* __restrict__ bo, const float* __restrict__ x, float* __restrict__ out)
{
  const int tid = threadIdx.x;
  const int lane = tid & 63, wave = tid >> 6;
  const int lq = lane & 15, lg = lane >> 4;
  const int bid = blockIdx.x;
  const int b = bid >> 6;
  const int tile = bid & 63;
  const int mblk = tile & 31, nblk = tile >> 5;       // M=4096(p), N=256(o)
  const int mbase = mblk*128 + (wave>>1)*64;
  const int nbase = nblk*128 + (wave&1)*64;
  const unsigned short* Amat = ws + OFF_AO + (size_t)b*S*CC;   // [p][c]
  const unsigned short* Bmat = ws + OFF_WO;                    // [o][c]

  f32x4 acc[4][4];
  #pragma unroll
  for (int i = 0; i < 4; i++)
    #pragma unroll
    for (int j = 0; j < 4; j++)
      acc[i][j] = (f32x4){0.f,0.f,0.f,0.f};

  const unsigned short* Arow = Amat + (size_t)(mbase + lq)*CC;
  const unsigned short* Brow = Bmat + (size_t)(nbase + lq)*CC;
  for (int ks = 0; ks < CC; ks += 32) {
    U8 af[4], bfr[4];
    #pragma unroll
    for (int mt = 0; mt < 4; mt++){
      const unsigned short* p = Arow + (size_t)mt*16*CC + ks + lg*4;
      af[mt].h[0] = *(const ushort4*)p;
      af[mt].h[1] = *(const ushort4*)(p + 16);
    }
    #pragma unroll
    for (int nt = 0; nt < 4; nt++){
      const unsigned short* p = Brow + (size_t)nt*16*CC + ks + lg*4;
      bfr[nt].h[0] = *(const ushort4*)p;
      bfr[nt].h[1] = *(const ushort4*)(p + 16);
    }
    #pragma unroll
    for (int mt = 0; mt < 4; mt++)
      #pragma unroll
      for (int nt = 0; nt < 4; nt++)
        acc[mt][nt] = MFMA16(af[mt].v, bfr[nt].v, acc[mt][nt]);
  }
  #pragma unroll
  for (int nt = 0; nt < 4; nt++){
    const int o = nbase + nt*16 + lq;
    const float bb = bo[o];
    #pragma unroll
    for (int mt = 0; mt < 4; mt++){
      const int p = mbase + mt*16 + lg*4;
      const size_t idx = ((size_t)b*CC + o)*S + p;
      const float4 xr = *(const float4*)(x + idx);
      f32x4 v = acc[mt][nt];
      float4 r; r.x = v[0]+bb+xr.x; r.y = v[1]+bb+xr.y; r.z = v[2]+bb+xr.z; r.w = v[3]+bb+xr.w;
      *(float4*)(out + idx) = r;
    }
  }
}

extern "C" void kernel_launch(void* const* d_in, const int* in_sizes, int n_in,
                              void* d_out, int out_size, void* d_ws, size_t ws_size,
                              hipStream_t stream) {
  const float* x  = (const float*)d_in[0];
  const float* y  = (const float*)d_in[1];
  const float* g1 = (const float*)d_in[2];
  const float* b1 = (const float*)d_in[3];
  const float* g2 = (const float*)d_in[4];
  const float* b2 = (const float*)d_in[5];
  const float* wq = (const float*)d_in[6];
  const float* bq = (const float*)d_in[7];
  const float* wk = (const float*)d_in[8];
  const float* bk = (const float*)d_in[9];
  const float* wv = (const float*)d_in[10];
  const float* bv = (const float*)d_in[11];
  const float* wo = (const float*)d_in[12];
  const float* bo = (const float*)d_in[13];
  float* out = (float*)d_out;
  unsigned short* ws16 = (unsigned short*)d_ws;

  convert_w  <<<256, 256, 0, stream>>>(wq, wk, wv, wo, ws16);
  groupnorm_k<<<128, 256, 0, stream>>>(x, y, g1, b1, g2, b2, ws16);
  qkv_gemm   <<<384, 256, 0, stream>>>(ws16, bq, bk, bv);
  attn_k     <<<512, 256, 0, stream>>>(ws16);
  outproj_k  <<<128, 256, 0, stream>>>(ws16, bo, x, out);
}

// Round 2
// 351.354 us; speedup vs baseline: 1.5541x; 1.5541x over previous
//
#include <hip/hip_runtime.h>

typedef __bf16 bf16_t;
typedef bf16_t bf16x8 __attribute__((ext_vector_type(8)));
typedef float f32x4 __attribute__((ext_vector_type(4)));

union U8 { bf16x8 v; ushort4 h[2]; };

__device__ __forceinline__ unsigned short f2bf(float f){
  unsigned int u = __builtin_bit_cast(unsigned int, f);
  u = (u + 0x7FFFu + ((u >> 16) & 1u)) >> 16;
  return (unsigned short)u;
}
__device__ __forceinline__ ushort4 pack4(f32x4 v){
  ushort4 r; r.x=f2bf(v[0]); r.y=f2bf(v[1]); r.z=f2bf(v[2]); r.w=f2bf(v[3]); return r;
}

#define MFMA16(a,b,c) __builtin_amdgcn_mfma_f32_16x16x32_bf16((a),(b),(c),0,0,0)

constexpr int BN = 2;      // batch
constexpr int CC = 256;    // channels
constexpr int S  = 4096;   // 64*64 spatial
constexpr int HH = 4;      // heads
constexpr int DD = 64;     // head dim

// ws layout (all bf16 stored as unsigned short)
constexpr size_t OFF_WQ = 0;
constexpr size_t OFF_WK = 65536;
constexpr size_t OFF_WV = 131072;
constexpr size_t OFF_WO = 196608;
constexpr size_t OFF_NY = 262144;                      // normed y: [b][p][c]
constexpr size_t OFF_NX = OFF_NY + (size_t)BN*S*CC;    // normed x: [b][p][c]
constexpr size_t OFF_Q  = OFF_NX + (size_t)BN*S*CC;    // [b][h][p][d]  (pre-scaled by 0.125*log2e)
constexpr size_t OFF_K  = OFF_Q  + (size_t)BN*S*CC;    // [b][h][p][d]
constexpr size_t OFF_V  = OFF_K  + (size_t)BN*S*CC;    // [b][c][p]  (channel-major = V^T)
constexpr size_t OFF_AO = OFF_V  + (size_t)BN*S*CC;    // attn out: [b][p][c]
// total = 12,845,056 ushort = 25,690,112 bytes

// ---------------- weight fp32 -> bf16 ----------------
__global__ __launch_bounds__(256) void convert_w(const float* __restrict__ wq, const float* __restrict__ wk,
    const float* __restrict__ wv, const float* __restrict__ wo, unsigned short* __restrict__ ws)
{
  const int idx = blockIdx.x*256 + threadIdx.x;      // 65536 threads, 4 floats each
  const int m = idx >> 14;
  const int off = (idx & 16383) << 2;
  const float* src = (m==0) ? wq : (m==1) ? wk : (m==2) ? wv : wo;
  float4 v = *(const float4*)(src + off);
  ushort4 r; r.x=f2bf(v.x); r.y=f2bf(v.y); r.z=f2bf(v.z); r.w=f2bf(v.w);
  *(ushort4*)(ws + (size_t)m*65536 + off) = r;
}

// ---------------- GroupNorm (32 groups of 8 ch), writes [p][c] bf16 ----------------
__global__ __launch_bounds__(256) void groupnorm_k(const float* __restrict__ x, const float* __restrict__ y,
    const float* __restrict__ g1, const float* __restrict__ b1,
    const float* __restrict__ g2, const float* __restrict__ b2,
    unsigned short* __restrict__ ws)
{
  const int tid = threadIdx.x;
  const int bid = blockIdx.x;
  const int tsel = bid >> 6;          // 0: x -> NX, 1: y -> NY
  const int rem  = bid & 63;
  const int b = rem >> 5, g = rem & 31;
  const float* in = (tsel ? y : x) + ((size_t)b*CC + g*8)*S;
  unsigned short* outp = ws + (tsel ? OFF_NY : OFF_NX) + (size_t)b*S*CC + g*8;
  const float* gamma = (tsel ? g2 : g1) + g*8;
  const float* beta  = (tsel ? b2 : b1) + g*8;

  float s = 0.f, ss = 0.f;
  #pragma unroll
  for (int ci = 0; ci < 8; ci++){
    const float4* row = (const float4*)(in + (size_t)ci*S);
    #pragma unroll
    for (int i = 0; i < 4; i++){
      float4 v = row[tid + i*256];
      s  += v.x + v.y + v.z + v.w;
      ss += v.x*v.x + v.y*v.y + v.z*v.z + v.w*v.w;
    }
  }
  #pragma unroll
  for (int off = 1; off < 64; off <<= 1){
    s  += __shfl_xor(s,  off);
    ss += __shfl_xor(ss, off);
  }
  __shared__ float red[8];
  __shared__ float mv[2];
  const int wave = tid >> 6, lane = tid & 63;
  if (lane == 0){ red[wave] = s; red[4+wave] = ss; }
  __syncthreads();
  if (tid == 0){
    float S1 = red[0]+red[1]+red[2]+red[3];
    float S2 = red[4]+red[5]+red[6]+red[7];
    const float invn = 1.0f/32768.0f;
    float mean = S1*invn;
    float var  = S2*invn - mean*mean;
    mv[0] = mean; mv[1] = rsqrtf(var + 1e-6f);
  }
  __syncthreads();
  const float mean = mv[0], rstd = mv[1];
  float sc[8], sh[8];
  #pragma unroll
  for (int ci = 0; ci < 8; ci++){ sc[ci] = rstd*gamma[ci]; sh[ci] = beta[ci] - mean*sc[ci]; }
  for (int i = 0; i < 16; i++){
    const int p = tid + i*256;
    ushort4 o0, o1;
    o0.x = f2bf(in[0*S+p]*sc[0]+sh[0]);
    o0.y = f2bf(in[1*S+p]*sc[1]+sh[1]);
    o0.z = f2bf(in[2*S+p]*sc[2]+sh[2]);
    o0.w = f2bf(in[3*S+p]*sc[3]+sh[3]);
    o1.x = f2bf(in[4*S+p]*sc[4]+sh[4]);
    o1.y = f2bf(in[5*S+p]*sc[5]+sh[5]);
    o1.z = f2bf(in[6*S+p]*sc[6]+sh[6]);
    o1.w = f2bf(in[7*S+p]*sc[7]+sh[7]);
    *(ushort4*)(outp + (size_t)p*CC)     = o0;
    *(ushort4*)(outp + (size_t)p*CC + 4) = o1;
  }
}

// ---------------- Q/K/V projection GEMMs ----------------
// which 0: Q = Wq x normY  -> [b][h][p][d], scaled by 0.125*log2(e)
// which 1: K = Wk x normX  -> [b][h][p][d]
// which 2: V = (normX x Wv^T)^T -> [b][c][p]  (computed transposed: D[p][o])
__global__ __launch_bounds__(256) void qkv_gemm(unsigned short* __restrict__ ws,
    const float* __restrict__ bq, const float* __restrict__ bk, const float* __restrict__ bv)
{
  const int tid = threadIdx.x;
  const int lane = tid & 63, wave = tid >> 6;
  const int lq = lane & 15, lg = lane >> 4;
  const int bid = blockIdx.x;
  const int inst = bid >> 6, tile = bid & 63;   // 6 instances x 64 tiles
  const int which = inst % 3, b = inst / 3;
  int mblk, nblk;
  if (which == 2) { mblk = tile & 31; nblk = tile >> 5; }   // M=4096(p), N=256(o)
  else            { mblk = tile >> 5; nblk = tile & 31; }   // M=256(o),  N=4096(p)
  const int mbase = mblk*128 + (wave>>1)*64;
  const int nbase = nblk*128 + (wave&1)*64;

  const unsigned short* Amat;
  const unsigned short* Bmat;
  if (which == 0)      { Amat = ws + OFF_WQ;                     Bmat = ws + OFF_NY + (size_t)b*S*CC; }
  else if (which == 1) { Amat = ws + OFF_WK;                     Bmat = ws + OFF_NX + (size_t)b*S*CC; }
  else                 { Amat = ws + OFF_NX + (size_t)b*S*CC;    Bmat = ws + OFF_WV; }

  f32x4 acc[4][4];
  #pragma unroll
  for (int i = 0; i < 4; i++)
    #pragma unroll
    for (int j = 0; j < 4; j++)
      acc[i][j] = (f32x4){0.f,0.f,0.f,0.f};

  const unsigned short* Arow = Amat + (size_t)(mbase + lq)*CC;
  const unsigned short* Brow = Bmat + (size_t)(nbase + lq)*CC;

  for (int ks = 0; ks < CC; ks += 32) {
    U8 af[4], bfr[4];
    #pragma unroll
    for (int mt = 0; mt < 4; mt++){
      const unsigned short* p = Arow + (size_t)mt*16*CC + ks + lg*4;
      af[mt].h[0] = *(const ushort4*)p;
      af[mt].h[1] = *(const ushort4*)(p + 16);
    }
    #pragma unroll
    for (int nt = 0; nt < 4; nt++){
      const unsigned short* p = Brow + (size_t)nt*16*CC + ks + lg*4;
      bfr[nt].h[0] = *(const ushort4*)p;
      bfr[nt].h[1] = *(const ushort4*)(p + 16);
    }
    #pragma unroll
    for (int mt = 0; mt < 4; mt++)
      #pragma unroll
      for (int nt = 0; nt < 4; nt++)
        acc[mt][nt] = MFMA16(af[mt].v, bfr[nt].v, acc[mt][nt]);
  }

  if (which < 2) {
    const float* bias = (which==0) ? bq : bk;
    const float scl = (which==0) ? 0.125f*1.44269504089f : 1.0f;
    unsigned short* Outp = ws + (which==0 ? OFF_Q : OFF_K) + (size_t)b*HH*S*DD;
    #pragma unroll
    for (int mt = 0; mt < 4; mt++){
      const int o = mbase + mt*16 + lg*4;
      const float4 bb = *(const float4*)(bias + o);
      const int h = o >> 6, db = o & 63;
      #pragma unroll
      for (int nt = 0; nt < 4; nt++){
        const int p = nbase + nt*16 + lq;
        f32x4 v = acc[mt][nt];
        ushort4 r;
        r.x = f2bf((v[0]+bb.x)*scl); r.y = f2bf((v[1]+bb.y)*scl);
        r.z = f2bf((v[2]+bb.z)*scl); r.w = f2bf((v[3]+bb.w)*scl);
        *(ushort4*)(Outp + ((size_t)h*S + p)*DD + db) = r;
      }
    }
  } else {
    unsigned short* Outp = ws + OFF_V + (size_t)b*CC*S;
    #pragma unroll
    for (int nt = 0; nt < 4; nt++){
      const int o = nbase + nt*16 + lq;
      const float bb = bv[o];
      #pragma unroll
      for (int mt = 0; mt < 4; mt++){
        const int p = mbase + mt*16 + lg*4;
        f32x4 v = acc[mt][nt];
        ushort4 r;
        r.x = f2bf(v[0]+bb); r.y = f2bf(v[1]+bb);
        r.z = f2bf(v[2]+bb); r.w = f2bf(v[3]+bb);
        *(ushort4*)(Outp + (size_t)o*S + p) = r;
      }
    }
  }
}

// ---------------- flash attention v2 ----------------
// 32 q per wave (2 Q frags), 4 waves/block (128 q), grid = 8 bh x 32 qblk = 256.
// K double-buffered in registers (prefetch t+1), V loaded under softmax shadow.
// Softmax in exp2 domain (Q pre-scaled by 0.125*log2e).
__device__ __forceinline__ void attn_tile(
    const unsigned short* __restrict__ Kp, const unsigned short* __restrict__ Vp,
    int t0, int tn, int lq, int lg,
    U8 (&kcur)[4][2], U8 (&kalt)[4][2],
    const U8 (&qf)[2][2],
    f32x4 (&acc)[4][2], float (&mr)[2], float (&lr)[2])
{
  __builtin_amdgcn_s_barrier();   // keep the block's 4 waves streaming the same K/V tile (L1 reuse)
  // prefetch K(tn) into kalt
  #pragma unroll
  for (int mt = 0; mt < 4; mt++){
    const unsigned short* p = Kp + (size_t)(tn + mt*16 + lq)*DD + lg*4;
    kalt[mt][0].h[0] = *(const ushort4*)p;
    kalt[mt][0].h[1] = *(const ushort4*)(p+16);
    kalt[mt][1].h[0] = *(const ushort4*)(p+32);
    kalt[mt][1].h[1] = *(const ushort4*)(p+48);
  }
  // QK^T for both q-frags: st[f][mt] = S^T[t0+mt*16+lg*4+r][qf]
  f32x4 st[2][4];
  #pragma unroll
  for (int f = 0; f < 2; f++)
    #pragma unroll
    for (int mt = 0; mt < 4; mt++){
      f32x4 z = (f32x4){0.f,0.f,0.f,0.f};
      z = MFMA16(kcur[mt][0].v, qf[f][0].v, z);
      z = MFMA16(kcur[mt][1].v, qf[f][1].v, z);
      st[f][mt] = z;
    }
  // V loads for this tile (consumed after softmax -> latency hidden)
  U8 vv[4][2];
  #pragma unroll
  for (int dt = 0; dt < 4; dt++){
    const unsigned short* p = Vp + (size_t)(dt*16 + lq)*S + t0 + lg*4;
    vv[dt][0].h[0] = *(const ushort4*)p;
    vv[dt][0].h[1] = *(const ushort4*)(p+16);
    vv[dt][1].h[0] = *(const ushort4*)(p+32);
    vv[dt][1].h[1] = *(const ushort4*)(p+48);
  }
  // online softmax (exp2 domain) per q-frag
  U8 pf[2][2];
  float cc[2];
  #pragma unroll
  for (int f = 0; f < 2; f++){
    float tm = st[f][0][0];
    #pragma unroll
    for (int mt = 0; mt < 4; mt++)
      #pragma unroll
      for (int r = 0; r < 4; r++)
        tm = fmaxf(tm, st[f][mt][r]);
    tm = fmaxf(tm, __shfl_xor(tm, 16));
    tm = fmaxf(tm, __shfl_xor(tm, 32));
    const float mnew = fmaxf(mr[f], tm);
    float ts = 0.f;
    #pragma unroll
    for (int mt = 0; mt < 4; mt++)
      #pragma unroll
      for (int r = 0; r < 4; r++){
        float e = __builtin_amdgcn_exp2f(st[f][mt][r] - mnew);
        st[f][mt][r] = e;
        ts += e;
      }
    ts += __shfl_xor(ts, 16);
    ts += __shfl_xor(ts, 32);
    cc[f] = __builtin_amdgcn_exp2f(mr[f] - mnew);
    lr[f] = lr[f]*cc[f] + ts;
    mr[f] = mnew;
    pf[f][0].h[0] = pack4(st[f][0]); pf[f][0].h[1] = pack4(st[f][1]);   // t 0..31
    pf[f][1].h[0] = pack4(st[f][2]); pf[f][1].h[1] = pack4(st[f][3]);   // t 32..63
  }
  // PV
  #pragma unroll
  for (int dt = 0; dt < 4; dt++)
    #pragma unroll
    for (int f = 0; f < 2; f++){
      f32x4 a = acc[dt][f];
      #pragma unroll
      for (int r = 0; r < 4; r++) a[r] *= cc[f];
      a = MFMA16(vv[dt][0].v, pf[f][0].v, a);
      a = MFMA16(vv[dt][1].v, pf[f][1].v, a);
      acc[dt][f] = a;
    }
}

__global__ __launch_bounds__(256) void attn_k(unsigned short* __restrict__ ws)
{
  const int tid = threadIdx.x;
  const int lane = tid & 63, wave = tid >> 6;
  const int lq = lane & 15, lg = lane >> 4;
  const int bid = blockIdx.x;
  const int bh = bid >> 5;                  // 8 (b,h) x 32 q-blocks of 128
  const int qblk = bid & 31;
  const int b = bh >> 2, h = bh & 3;
  const unsigned short* Qp = ws + OFF_Q + (size_t)bh*S*DD;
  const unsigned short* Kp = ws + OFF_K + (size_t)bh*S*DD;
  const unsigned short* Vp = ws + OFF_V + ((size_t)b*CC + h*DD)*S;
  unsigned short* AOp = ws + OFF_AO + (size_t)b*S*CC;
  const int qb = qblk*128 + wave*32;        // wave's 32 q columns

  U8 qf[2][2];
  #pragma unroll
  for (int f = 0; f < 2; f++){
    const unsigned short* p = Qp + (size_t)(qb + f*16 + lq)*DD + lg*4;
    qf[f][0].h[0] = *(const ushort4*)p;      qf[f][0].h[1] = *(const ushort4*)(p+16);
    qf[f][1].h[0] = *(const ushort4*)(p+32); qf[f][1].h[1] = *(const ushort4*)(p+48);
  }
  f32x4 acc[4][2];
  #pragma unroll
  for (int i = 0; i < 4; i++)
    #pragma unroll
    for (int f = 0; f < 2; f++)
      acc[i][f] = (f32x4){0.f,0.f,0.f,0.f};
  float mr[2] = {-1e30f, -1e30f};
  float lr[2] = {0.f, 0.f};

  U8 kA[4][2], kB[4][2];
  // prologue: load K(0) into kA
  #pragma unroll
  for (int mt = 0; mt < 4; mt++){
    const unsigned short* p = Kp + (size_t)(mt*16 + lq)*DD + lg*4;
    kA[mt][0].h[0] = *(const ushort4*)p;
    kA[mt][0].h[1] = *(const ushort4*)(p+16);
    kA[mt][1].h[0] = *(const ushort4*)(p+32);
    kA[mt][1].h[1] = *(const ushort4*)(p+48);
  }
  for (int t0 = 0; t0 < S; t0 += 128){
    attn_tile(Kp, Vp, t0,      t0+64,           lq, lg, kA, kB, qf, acc, mr, lr);
    attn_tile(Kp, Vp, t0+64,  (t0+128)&(S-1),   lq, lg, kB, kA, qf, acc, mr, lr);
  }

  #pragma unroll
  for (int f = 0; f < 2; f++){
    const float inv = 1.0f / lr[f];
    const int q = qb + f*16 + lq;
    #pragma unroll
    for (int dt = 0; dt < 4; dt++){
      f32x4 v;
      #pragma unroll
      for (int r = 0; r < 4; r++) v[r] = acc[dt][f][r] * inv;
      *(ushort4*)(AOp + (size_t)q*CC + h*DD + dt*16 + lg*4) = pack4(v);
    }
  }
}

// ---------------- output projection + residual ----------------
// D[p][o] = AO[p][:] . wo[o][:] ; out = D + bo + x
__global__ __launch_bounds__(256) void outproj_k(const unsigned short* __restrict__ ws,
    const float* __restrict__ bo, const float* __restrict__ x, float* __restrict__ out)
{
  const int tid = threadIdx.x;
  const int lane = tid & 63, wave = tid >> 6;
  const int lq = lane & 15, lg = lane >> 4;
  const int bid = blockIdx.x;
  const int b = bid >> 6;
  const int tile = bid & 63;
  const int mblk = tile & 31, nblk = tile >> 5;       // M=4096(p), N=256(o)
  const int mbase = mblk*128 + (wave>>1)*64;
  const int nbase = nblk*128 + (wave&1)*64;
  const unsigned short* Amat = ws + OFF_AO + (size_t)b*S*CC;   // [p][c]
  const unsigned short* Bmat = ws + OFF_WO;                    // [o][c]

  f32x4 acc[4][4];
  #pragma unroll
  for (int i = 0; i < 4; i++)
    #pragma unroll
    for (int j = 0; j < 4; j++)
      acc[i][j] = (f32x4){0.f,0.f,0.f,0.f};

  const unsigned short* Arow = Amat + (size_t)(mbase + lq)*CC;
  const unsigned short* Brow = Bmat + (size_t)(nbase + lq)*CC;
  for (int ks = 0; ks < CC; ks += 32) {
    U8 af[4], bfr[4];
    #pragma unroll
    for (int mt = 0; mt < 4; mt++){
      const unsigned short* p = Arow + (size_t)mt*16*CC + ks + lg*4;
      af[mt].h[0] = *(const ushort4*)p;
      af[mt].h[1] = *(const ushort4*)(p + 16);
    }
    #pragma unroll
    for (int nt = 0; nt < 4; nt++){
      const unsigned short* p = Brow + (size_t)nt*16*CC + ks + lg*4;
      bfr[nt].h[0] = *(const ushort4*)p;
      bfr[nt].h[1] = *(const ushort4*)(p + 16);
    }
    #pragma unroll
    for (int mt = 0; mt < 4; mt++)
      #pragma unroll
      for (int nt = 0; nt < 4; nt++)
        acc[mt][nt] = MFMA16(af[mt].v, bfr[nt].v, acc[mt][nt]);
  }
  #pragma unroll
  for (int nt = 0; nt < 4; nt++){
    const int o = nbase + nt*16 + lq;
    const float bb = bo[o];
    #pragma unroll
    for (int mt = 0; mt < 4; mt++){
      const int p = mbase + mt*16 + lg*4;
      const size_t idx = ((size_t)b*CC + o)*S + p;
      const float4 xr = *(const float4*)(x + idx);
      f32x4 v = acc[mt][nt];
      float4 r; r.x = v[0]+bb+xr.x; r.y = v[1]+bb+xr.y; r.z = v[2]+bb+xr.z; r.w = v[3]+bb+xr.w;
      *(float4*)(out + idx) = r;
    }
  }
}

extern "C" void kernel_launch(void* const* d_in, const int* in_sizes, int n_in,
                              void* d_out, int out_size, void* d_ws, size_t ws_size,
                              hipStream_t stream) {
  const float* x  = (const float*)d_in[0];
  const float* y  = (const float*)d_in[1];
  const float* g1 = (const float*)d_in[2];
  const float* b1 = (const float*)d_in[3];
  const float* g2 = (const float*)d_in[4];
  const float* b2 = (const float*)d_in[5];
  const float* wq = (const float*)d_in[6];
  const float* bq = (const float*)d_in[7];
  const float* wk = (const float*)d_in[8];
  const float* bk = (const float*)d_in[9];
  const float* wv = (const float*)d_in[10];
  const float* bv = (const float*)d_in[11];
  const float* wo = (const float*)d_in[12];
  const float* bo = (const float*)d_in[13];
  float* out = (float*)d_out;
  unsigned short* ws16 = (unsigned short*)d_ws;

  convert_w  <<<256, 256, 0, stream>>>(wq, wk, wv, wo, ws16);
  groupnorm_k<<<128, 256, 0, stream>>>(x, y, g1, b1, g2, b2, ws16);
  qkv_gemm   <<<384, 256, 0, stream>>>(ws16, bq, bk, bv);
  attn_k     <<<256, 256, 0, stream>>>(ws16);
  outproj_k  <<<128, 256, 0, stream>>>(ws16, bo, x, out);
}

// Round 3
// 154.234 us; speedup vs baseline: 3.5402x; 2.2781x over previous
//
#include <hip/hip_runtime.h>

typedef __bf16 bf16_t;
typedef bf16_t bf16x8 __attribute__((ext_vector_type(8)));
typedef float f32x4 __attribute__((ext_vector_type(4)));

#define MFMA16(a,b,c) __builtin_amdgcn_mfma_f32_16x16x32_bf16((a),(b),(c),0,0,0)

#define GLOAD_LDS16(gsrc, ldst) \
  __builtin_amdgcn_global_load_lds((const __attribute__((address_space(1))) unsigned int*)(gsrc), \
                                   (__attribute__((address_space(3))) unsigned int*)(ldst), 16, 0, 0)

__device__ __forceinline__ unsigned short f2bf(float f){
  unsigned int u = __builtin_bit_cast(unsigned int, f);
  u = (u + 0x7FFFu + ((u >> 16) & 1u)) >> 16;
  return (unsigned short)u;
}
__device__ __forceinline__ ushort4 pk4(f32x4 v){
  union { __bf16 b[4]; ushort4 u; } r;
  r.b[0]=(__bf16)v[0]; r.b[1]=(__bf16)v[1]; r.b[2]=(__bf16)v[2]; r.b[3]=(__bf16)v[3];
  return r.u;
}

// k-interleave: within each 64-elem segment, 8B-glob gi -> position so that a
// contiguous 16B read at (h*32 + lg*8) elems yields globs {lg, 4+lg} of k-half h,
// i.e. exactly the MFMA 16x16x32 A/B fragment k-pattern (k=lg*4+{0..3}, lg*4+16+{0..3}).
__device__ __forceinline__ int KI(int d){   // d must be 4-aligned
  int gi = (d >> 2) & 15;
  int pos = (gi & 8) | ((gi & 3) << 1) | ((gi >> 2) & 1);
  return (d & ~63) | (pos << 2);
}

constexpr int BN = 2;      // batch
constexpr int CC = 256;    // channels
constexpr int S  = 4096;   // 64*64 spatial
constexpr int HH = 4;      // heads
constexpr int DD = 64;     // head dim

// ws layout (bf16 as unsigned short). ALL tensors k-interleaved along their GEMM k-dim.
constexpr size_t OFF_WQ = 0;
constexpr size_t OFF_WK = 65536;
constexpr size_t OFF_WV = 131072;
constexpr size_t OFF_WO = 196608;
constexpr size_t OFF_NY = 262144;                      // normed y: [b][p][c~]
constexpr size_t OFF_NX = OFF_NY + (size_t)BN*S*CC;    // normed x: [b][p][c~]
constexpr size_t OFF_Q  = OFF_NX + (size_t)BN*S*CC;    // [b][h][p][d~] (pre-scaled 0.125*log2e)
constexpr size_t OFF_K  = OFF_Q  + (size_t)BN*S*CC;    // [b][h][p][d~]
constexpr size_t OFF_V  = OFF_K  + (size_t)BN*S*CC;    // [b][c][p~]  (channel-major = V^T)
constexpr size_t OFF_AO = OFF_V  + (size_t)BN*S*CC;    // attn out: [b][p][c~]

// ---------------- weight fp32 -> bf16 (k-interleaved) ----------------
__global__ __launch_bounds__(256) void convert_w(const float* __restrict__ wq, const float* __restrict__ wk,
    const float* __restrict__ wv, const float* __restrict__ wo, unsigned short* __restrict__ ws)
{
  const int idx = blockIdx.x*256 + threadIdx.x;
  const int m = idx >> 14;
  const int off = (idx & 16383) << 2;          // 4-aligned elem index in [o][c]
  const float* src = (m==0) ? wq : (m==1) ? wk : (m==2) ? wv : wo;
  float4 v = *(const float4*)(src + off);
  ushort4 r; r.x=f2bf(v.x); r.y=f2bf(v.y); r.z=f2bf(v.z); r.w=f2bf(v.w);
  const int off2 = (off & ~255) | KI(off & 255);
  *(ushort4*)(ws + (size_t)m*65536 + off2) = r;
}

// ---------------- GroupNorm, writes [p][c~] bf16 ----------------
__global__ __launch_bounds__(256) void groupnorm_k(const float* __restrict__ x, const float* __restrict__ y,
    const float* __restrict__ g1, const float* __restrict__ b1,
    const float* __restrict__ g2, const float* __restrict__ b2,
    unsigned short* __restrict__ ws)
{
  const int tid = threadIdx.x;
  const int bid = blockIdx.x;
  const int tsel = bid >> 6;
  const int rem  = bid & 63;
  const int b = rem >> 5, g = rem & 31;
  const float* in = (tsel ? y : x) + ((size_t)b*CC + g*8)*S;
  unsigned short* outp = ws + (tsel ? OFF_NY : OFF_NX) + (size_t)b*S*CC;
  const int o0 = KI(g*8), o1 = KI(g*8+4);
  const float* gamma = (tsel ? g2 : g1) + g*8;
  const float* beta  = (tsel ? b2 : b1) + g*8;

  float s = 0.f, ss = 0.f;
  #pragma unroll
  for (int ci = 0; ci < 8; ci++){
    const float4* row = (const float4*)(in + (size_t)ci*S);
    #pragma unroll
    for (int i = 0; i < 4; i++){
      float4 v = row[tid + i*256];
      s  += v.x + v.y + v.z + v.w;
      ss += v.x*v.x + v.y*v.y + v.z*v.z + v.w*v.w;
    }
  }
  #pragma unroll
  for (int off = 1; off < 64; off <<= 1){
    s  += __shfl_xor(s,  off);
    ss += __shfl_xor(ss, off);
  }
  __shared__ float red[8];
  __shared__ float mv[2];
  const int wave = tid >> 6, lane = tid & 63;
  if (lane == 0){ red[wave] = s; red[4+wave] = ss; }
  __syncthreads();
  if (tid == 0){
    float S1 = red[0]+red[1]+red[2]+red[3];
    float S2 = red[4]+red[5]+red[6]+red[7];
    const float invn = 1.0f/32768.0f;
    float mean = S1*invn;
    float var  = S2*invn - mean*mean;
    mv[0] = mean; mv[1] = rsqrtf(var + 1e-6f);
  }
  __syncthreads();
  const float mean = mv[0], rstd = mv[1];
  float sc[8], sh[8];
  #pragma unroll
  for (int ci = 0; ci < 8; ci++){ sc[ci] = rstd*gamma[ci]; sh[ci] = beta[ci] - mean*sc[ci]; }
  for (int i = 0; i < 16; i++){
    const int p = tid + i*256;
    ushort4 a0, a1;
    a0.x = f2bf(in[0*S+p]*sc[0]+sh[0]);
    a0.y = f2bf(in[1*S+p]*sc[1]+sh[1]);
    a0.z = f2bf(in[2*S+p]*sc[2]+sh[2]);
    a0.w = f2bf(in[3*S+p]*sc[3]+sh[3]);
    a1.x = f2bf(in[4*S+p]*sc[4]+sh[4]);
    a1.y = f2bf(in[5*S+p]*sc[5]+sh[5]);
    a1.z = f2bf(in[6*S+p]*sc[6]+sh[6]);
    a1.w = f2bf(in[7*S+p]*sc[7]+sh[7]);
    *(ushort4*)(outp + (size_t)p*CC + o0) = a0;
    *(ushort4*)(outp + (size_t)p*CC + o1) = a1;
  }
}

// ---------------- Q/K/V projection GEMMs (interleaved in & out) ----------------
__global__ __launch_bounds__(256) void qkv_gemm(unsigned short* __restrict__ ws,
    const float* __restrict__ bq, const float* __restrict__ bk, const float* __restrict__ bv)
{
  const int tid = threadIdx.x;
  const int lane = tid & 63, wave = tid >> 6;
  const int lq = lane & 15, lg = lane >> 4;
  const int bid = blockIdx.x;
  const int inst = bid >> 6, tile = bid & 63;
  const int which = inst % 3, b = inst / 3;
  int mblk, nblk;
  if (which == 2) { mblk = tile & 31; nblk = tile >> 5; }
  else            { mblk = tile >> 5; nblk = tile & 31; }
  const int mbase = mblk*128 + (wave>>1)*64;
  const int nbase = nblk*128 + (wave&1)*64;

  const unsigned short* Amat;
  const unsigned short* Bmat;
  if (which == 0)      { Amat = ws + OFF_WQ;                   Bmat = ws + OFF_NY + (size_t)b*S*CC; }
  else if (which == 1) { Amat = ws + OFF_WK;                   Bmat = ws + OFF_NX + (size_t)b*S*CC; }
  else                 { Amat = ws + OFF_NX + (size_t)b*S*CC;  Bmat = ws + OFF_WV; }

  f32x4 acc[4][4];
  #pragma unroll
  for (int i = 0; i < 4; i++)
    #pragma unroll
    for (int j = 0; j < 4; j++)
      acc[i][j] = (f32x4){0.f,0.f,0.f,0.f};

  const unsigned short* Arow = Amat + (size_t)(mbase + lq)*CC + lg*8;
  const unsigned short* Brow = Bmat + (size_t)(nbase + lq)*CC + lg*8;

  for (int ks = 0; ks < CC; ks += 32) {
    bf16x8 af[4], bfr[4];
    #pragma unroll
    for (int mt = 0; mt < 4; mt++)
      af[mt] = *(const bf16x8*)(Arow + (size_t)mt*16*CC + ks);
    #pragma unroll
    for (int nt = 0; nt < 4; nt++)
      bfr[nt] = *(const bf16x8*)(Brow + (size_t)nt*16*CC + ks);
    #pragma unroll
    for (int mt = 0; mt < 4; mt++)
      #pragma unroll
      for (int nt = 0; nt < 4; nt++)
        acc[mt][nt] = MFMA16(af[mt], bfr[nt], acc[mt][nt]);
  }

  if (which < 2) {
    const float* bias = (which==0) ? bq : bk;
    const float scl = (which==0) ? 0.125f*1.44269504089f : 1.0f;
    unsigned short* Outp = ws + (which==0 ? OFF_Q : OFF_K) + (size_t)b*HH*S*DD;
    #pragma unroll
    for (int mt = 0; mt < 4; mt++){
      const int o = mbase + mt*16 + lg*4;
      const float4 bb = *(const float4*)(bias + o);
      const int hd = o >> 6, db = KI(o & 63);
      #pragma unroll
      for (int nt = 0; nt < 4; nt++){
        const int p = nbase + nt*16 + lq;
        f32x4 v = acc[mt][nt];
        ushort4 r;
        r.x = f2bf((v[0]+bb.x)*scl); r.y = f2bf((v[1]+bb.y)*scl);
        r.z = f2bf((v[2]+bb.z)*scl); r.w = f2bf((v[3]+bb.w)*scl);
        *(ushort4*)(Outp + ((size_t)hd*S + p)*DD + db) = r;
      }
    }
  } else {
    unsigned short* Outp = ws + OFF_V + (size_t)b*CC*S;
    #pragma unroll
    for (int nt = 0; nt < 4; nt++){
      const int o = nbase + nt*16 + lq;
      const float bb = bv[o];
      #pragma unroll
      for (int mt = 0; mt < 4; mt++){
        const int p = mbase + mt*16 + lg*4;
        f32x4 v = acc[mt][nt];
        ushort4 r;
        r.x = f2bf(v[0]+bb); r.y = f2bf(v[1]+bb);
        r.z = f2bf(v[2]+bb); r.w = f2bf(v[3]+bb);
        *(ushort4*)(Outp + (size_t)o*S + KI(p)) = r;
      }
    }
  }
}

// ---------------- flash attention v3: LDS-staged K/V, 2-phase double buffer ----------------
// Block: 4 waves x 32 q = 128 q. Grid: 8 bh x 32 qblk = 256.
// K tile [64t][64d~] and V tile [64d][64t~] staged via global_load_lds (coalesced,
// source pre-XOR-swizzled chunk^=row&7), fragments via swizzled ds_read_b128.
__global__ __launch_bounds__(256) void attn_k(unsigned short* __restrict__ ws)
{
  __shared__ __align__(1024) char lds[32768];   // K dbuf @0/8192, V dbuf @16384/24576
  const int tid = threadIdx.x;
  const int lane = tid & 63, wave = tid >> 6;
  const int lq = lane & 15, lg = lane >> 4;
  const int rsw = (lq & 7) << 4;
  const int bid = blockIdx.x;
  const int bh = bid >> 5;
  const int qblk = bid & 31;
  const int b = bh >> 2, h = bh & 3;
  const unsigned short* Qp = ws + OFF_Q + (size_t)bh*S*DD;
  const unsigned short* Kp = ws + OFF_K + (size_t)bh*S*DD;
  const unsigned short* Vp = ws + OFF_V + ((size_t)b*CC + h*DD)*S;
  unsigned short* AOp = ws + OFF_AO + (size_t)b*S*CC;
  const int qb = qblk*128 + wave*32;

  // Q fragments: interleaved layout -> two b128 per frag
  bf16x8 qf[2][2];
  #pragma unroll
  for (int f = 0; f < 2; f++)
    #pragma unroll
    for (int hh = 0; hh < 2; hh++)
      qf[f][hh] = *(const bf16x8*)(Qp + (size_t)(qb + f*16 + lq)*DD + hh*32 + lg*8);

  // staging lane constants: row within tile, pre-swizzled source chunk
  const int csel = ((lane & 7) ^ (lane >> 3)) * 8;   // elem offset of this lane's 16B chunk
  const int srow = wave*16 + (lane >> 3);            // tile row (+j*8)

  f32x4 acc[4][2];
  #pragma unroll
  for (int i = 0; i < 4; i++)
    #pragma unroll
    for (int f = 0; f < 2; f++)
      acc[i][f] = (f32x4){0.f,0.f,0.f,0.f};
  float mr[2] = {-1e30f, -1e30f};
  float lr[2] = {0.f, 0.f};

  // prologue: stage tile 0 into buf 0
  #pragma unroll
  for (int j = 0; j < 2; j++){
    const int row = srow + j*8;
    GLOAD_LDS16(Kp + (size_t)row*DD + csel,  lds + wave*2048 + j*1024);
    GLOAD_LDS16(Vp + (size_t)row*S  + csel,  lds + 16384 + wave*2048 + j*1024);
  }
  __syncthreads();

  int cur = 0;
  for (int t0 = 0; t0 < S; t0 += 64){
    const char* kb = lds + cur*8192;
    const char* vb = lds + 16384 + cur*8192;
    // stage next tile into the other buffer
    if (t0 + 64 < S){
      char* kn = lds + (cur^1)*8192;
      char* vn = lds + 16384 + (cur^1)*8192;
      #pragma unroll
      for (int j = 0; j < 2; j++){
        const int row = srow + j*8;
        GLOAD_LDS16(Kp + (size_t)(t0 + 64 + row)*DD + csel, kn + wave*2048 + j*1024);
        GLOAD_LDS16(Vp + (size_t)row*S + (t0 + 64) + csel,  vn + wave*2048 + j*1024);
      }
    }
    // K fragments + QK^T
    bf16x8 kf[4][2];
    #pragma unroll
    for (int mt = 0; mt < 4; mt++)
      #pragma unroll
      for (int hh = 0; hh < 2; hh++)
        kf[mt][hh] = *(const bf16x8*)(kb + mt*2048 + lq*128 + ((hh*64 + lg*16) ^ rsw));
    f32x4 st[2][4];
    #pragma unroll
    for (int f = 0; f < 2; f++)
      #pragma unroll
      for (int mt = 0; mt < 4; mt++){
        f32x4 z = (f32x4){0.f,0.f,0.f,0.f};
        z = MFMA16(kf[mt][0], qf[f][0], z);
        z = MFMA16(kf[mt][1], qf[f][1], z);
        st[f][mt] = z;
      }
    // V fragments (issued before softmax, consumed after -> LDS latency hidden)
    bf16x8 vf[4][2];
    #pragma unroll
    for (int dt = 0; dt < 4; dt++)
      #pragma unroll
      for (int th = 0; th < 2; th++)
        vf[dt][th] = *(const bf16x8*)(vb + dt*2048 + lq*128 + ((th*64 + lg*16) ^ rsw));
    // online softmax (exp2 domain)
    bf16x8 pfr[2][2];
    float cc[2];
    #pragma unroll
    for (int f = 0; f < 2; f++){
      float m01 = fmaxf(fmaxf(st[f][0][0], st[f][0][1]), fmaxf(st[f][0][2], st[f][0][3]));
      float m23 = fmaxf(fmaxf(st[f][1][0], st[f][1][1]), fmaxf(st[f][1][2], st[f][1][3]));
      float m45 = fmaxf(fmaxf(st[f][2][0], st[f][2][1]), fmaxf(st[f][2][2], st[f][2][3]));
      float m67 = fmaxf(fmaxf(st[f][3][0], st[f][3][1]), fmaxf(st[f][3][2], st[f][3][3]));
      float tm = fmaxf(fmaxf(m01, m23), fmaxf(m45, m67));
      tm = fmaxf(tm, __shfl_xor(tm, 16));
      tm = fmaxf(tm, __shfl_xor(tm, 32));
      const float mnew = fmaxf(mr[f], tm);
      float ts = 0.f;
      union PU { bf16x8 v; __bf16 e[8]; } p0, p1;
      #pragma unroll
      for (int mt = 0; mt < 4; mt++)
        #pragma unroll
        for (int r = 0; r < 4; r++){
          float e = __builtin_amdgcn_exp2f(st[f][mt][r] - mnew);
          ts += e;
          if (mt < 2) p0.e[mt*4+r] = (__bf16)e;
          else        p1.e[(mt-2)*4+r] = (__bf16)e;
        }
      ts += __shfl_xor(ts, 16);
      ts += __shfl_xor(ts, 32);
      cc[f] = __builtin_amdgcn_exp2f(mr[f] - mnew);
      lr[f] = lr[f]*cc[f] + ts;
      mr[f] = mnew;
      pfr[f][0] = p0.v; pfr[f][1] = p1.v;
    }
    // PV
    #pragma unroll
    for (int dt = 0; dt < 4; dt++)
      #pragma unroll
      for (int f = 0; f < 2; f++){
        f32x4 a = acc[dt][f];
        #pragma unroll
        for (int r = 0; r < 4; r++) a[r] *= cc[f];
        a = MFMA16(vf[dt][0], pfr[f][0], a);
        a = MFMA16(vf[dt][1], pfr[f][1], a);
        acc[dt][f] = a;
      }
    __syncthreads();   // drains vmcnt(0): next-tile staging complete; LDS reads consumed
    cur ^= 1;
  }

  #pragma unroll
  for (int f = 0; f < 2; f++){
    const float inv = 1.0f / lr[f];
    const int q = qb + f*16 + lq;
    #pragma unroll
    for (int dt = 0; dt < 4; dt++){
      f32x4 v;
      #pragma unroll
      for (int r = 0; r < 4; r++) v[r] = acc[dt][f][r] * inv;
      *(ushort4*)(AOp + (size_t)q*CC + KI(h*64 + dt*16 + lg*4)) = pk4(v);
    }
  }
}

// ---------------- output projection + residual ----------------
__global__ __launch_bounds__(256) void outproj_k(const unsigned short* __restrict__ ws,
    const float* __restrict__ bo, const float* __restrict__ x, float* __restrict__ out)
{
  const int tid = threadIdx.x;
  const int lane = tid & 63, wave = tid >> 6;
  const int lq = lane & 15, lg = lane >> 4;
  const int bid = blockIdx.x;
  const int b = bid >> 6;
  const int tile = bid & 63;
  const int mblk = tile & 31, nblk = tile >> 5;
  const int mbase = mblk*128 + (wave>>1)*64;
  const int nbase = nblk*128 + (wave&1)*64;
  const unsigned short* Amat = ws + OFF_AO + (size_t)b*S*CC;
  const unsigned short* Bmat = ws + OFF_WO;

  f32x4 acc[4][4];
  #pragma unroll
  for (int i = 0; i < 4; i++)
    #pragma unroll
    for (int j = 0; j < 4; j++)
      acc[i][j] = (f32x4){0.f,0.f,0.f,0.f};

  const unsigned short* Arow = Amat + (size_t)(mbase + lq)*CC + lg*8;
  const unsigned short* Brow = Bmat + (size_t)(nbase + lq)*CC + lg*8;
  for (int ks = 0; ks < CC; ks += 32) {
    bf16x8 af[4], bfr[4];
    #pragma unroll
    for (int mt = 0; mt < 4; mt++)
      af[mt] = *(const bf16x8*)(Arow + (size_t)mt*16*CC + ks);
    #pragma unroll
    for (int nt = 0; nt < 4; nt++)
      bfr[nt] = *(const bf16x8*)(Brow + (size_t)nt*16*CC + ks);
    #pragma unroll
    for (int mt = 0; mt < 4; mt++)
      #pragma unroll
      for (int nt = 0; nt < 4; nt++)
        acc[mt][nt] = MFMA16(af[mt], bfr[nt], acc[mt][nt]);
  }
  #pragma unroll
  for (int nt = 0; nt < 4; nt++){
    const int o = nbase + nt*16 + lq;
    const float bb = bo[o];
    #pragma unroll
    for (int mt = 0; mt < 4; mt++){
      const int p = mbase + mt*16 + lg*4;
      const size_t idx = ((size_t)b*CC + o)*S + p;
      const float4 xr = *(const float4*)(x + idx);
      f32x4 v = acc[mt][nt];
      float4 r; r.x = v[0]+bb+xr.x; r.y = v[1]+bb+xr.y; r.z = v[2]+bb+xr.z; r.w = v[3]+bb+xr.w;
      *(float4*)(out + idx) = r;
    }
  }
}

extern "C" void kernel_launch(void* const* d_in, const int* in_sizes, int n_in,
                              void* d_out, int out_size, void* d_ws, size_t ws_size,
                              hipStream_t stream) {
  const float* x  = (const float*)d_in[0];
  const float* y  = (const float*)d_in[1];
  const float* g1 = (const float*)d_in[2];
  const float* b1 = (const float*)d_in[3];
  const float* g2 = (const float*)d_in[4];
  const float* b2 = (const float*)d_in[5];
  const float* wq = (const float*)d_in[6];
  const float* bq = (const float*)d_in[7];
  const float* wk = (const float*)d_in[8];
  const float* bk = (const float*)d_in[9];
  const float* wv = (const float*)d_in[10];
  const float* bv = (const float*)d_in[11];
  const float* wo = (const float*)d_in[12];
  const float* bo = (const float*)d_in[13];
  float* out = (float*)d_out;
  unsigned short* ws16 = (unsigned short*)d_ws;

  convert_w  <<<256, 256, 0, stream>>>(wq, wk, wv, wo, ws16);
  groupnorm_k<<<128, 256, 0, stream>>>(x, y, g1, b1, g2, b2, ws16);
  qkv_gemm   <<<384, 256, 0, stream>>>(ws16, bq, bk, bv);
  attn_k     <<<256, 256, 0, stream>>>(ws16);
  outproj_k  <<<128, 256, 0, stream>>>(ws16, bo, x, out);
}

// Round 4
// 141.050 us; speedup vs baseline: 3.8711x; 1.0935x over previous
//
#include <hip/hip_runtime.h>

typedef __bf16 bf16_t;
typedef bf16_t bf16x8 __attribute__((ext_vector_type(8)));
typedef float f32x4 __attribute__((ext_vector_type(4)));

#define MFMA16(a,b,c) __builtin_amdgcn_mfma_f32_16x16x32_bf16((a),(b),(c),0,0,0)

#define GLOAD_LDS16(gsrc, ldst) \
  __builtin_amdgcn_global_load_lds((const __attribute__((address_space(1))) unsigned int*)(gsrc), \
                                   (__attribute__((address_space(3))) unsigned int*)(ldst), 16, 0, 0)

__device__ __forceinline__ unsigned short f2bf(float f){
  unsigned int u = __builtin_bit_cast(unsigned int, f);
  u = (u + 0x7FFFu + ((u >> 16) & 1u)) >> 16;
  return (unsigned short)u;
}
__device__ __forceinline__ ushort4 pk4(f32x4 v){
  union { __bf16 b[4]; ushort4 u; } r;
  r.b[0]=(__bf16)v[0]; r.b[1]=(__bf16)v[1]; r.b[2]=(__bf16)v[2]; r.b[3]=(__bf16)v[3];
  return r.u;
}

// k-interleave: within each 64-elem segment, 8B-glob gi -> position so that a
// contiguous 16B read at (h*32 + lg*8) elems yields globs {lg, 4+lg} of k-half h,
// i.e. exactly the MFMA 16x16x32 A/B fragment k-pattern.
__device__ __forceinline__ int KI(int d){   // d must be 4-aligned
  int gi = (d >> 2) & 15;
  int pos = (gi & 8) | ((gi & 3) << 1) | ((gi >> 2) & 1);
  return (d & ~63) | (pos << 2);
}

constexpr int BN = 2;      // batch
constexpr int CC = 256;    // channels
constexpr int S  = 4096;   // 64*64 spatial
constexpr int HH = 4;      // heads
constexpr int DD = 64;     // head dim

// ws layout (bf16 as unsigned short). ALL tensors k-interleaved along their GEMM k-dim.
constexpr size_t OFF_WQ = 0;
constexpr size_t OFF_WK = 65536;
constexpr size_t OFF_WV = 131072;
constexpr size_t OFF_WO = 196608;
constexpr size_t OFF_NY = 262144;                      // normed y: [b][p][c~]
constexpr size_t OFF_NX = OFF_NY + (size_t)BN*S*CC;    // normed x: [b][p][c~]
constexpr size_t OFF_Q  = OFF_NX + (size_t)BN*S*CC;    // [b][h][p][d~] (pre-scaled 0.125*log2e)
constexpr size_t OFF_K  = OFF_Q  + (size_t)BN*S*CC;    // [b][h][p][d~]
constexpr size_t OFF_V  = OFF_K  + (size_t)BN*S*CC;    // [b][c][p~]  (channel-major = V^T)
constexpr size_t OFF_AO = OFF_V  + (size_t)BN*S*CC;    // attn out: [b][p][c~]

// ---------------- weight fp32 -> bf16 (k-interleaved) ----------------
__global__ __launch_bounds__(256) void convert_w(const float* __restrict__ wq, const float* __restrict__ wk,
    const float* __restrict__ wv, const float* __restrict__ wo, unsigned short* __restrict__ ws)
{
  const int idx = blockIdx.x*256 + threadIdx.x;
  const int m = idx >> 14;
  const int off = (idx & 16383) << 2;          // 4-aligned elem index in [o][c]
  const float* src = (m==0) ? wq : (m==1) ? wk : (m==2) ? wv : wo;
  float4 v = *(const float4*)(src + off);
  ushort4 r; r.x=f2bf(v.x); r.y=f2bf(v.y); r.z=f2bf(v.z); r.w=f2bf(v.w);
  const int off2 = (off & ~255) | KI(off & 255);
  *(ushort4*)(ws + (size_t)m*65536 + off2) = r;
}

// ---------------- GroupNorm, writes [p][c~] bf16 ----------------
__global__ __launch_bounds__(256) void groupnorm_k(const float* __restrict__ x, const float* __restrict__ y,
    const float* __restrict__ g1, const float* __restrict__ b1,
    const float* __restrict__ g2, const float* __restrict__ b2,
    unsigned short* __restrict__ ws)
{
  const int tid = threadIdx.x;
  const int bid = blockIdx.x;
  const int tsel = bid >> 6;
  const int rem  = bid & 63;
  const int b = rem >> 5, g = rem & 31;
  const float* in = (tsel ? y : x) + ((size_t)b*CC + g*8)*S;
  unsigned short* outp = ws + (tsel ? OFF_NY : OFF_NX) + (size_t)b*S*CC;
  const int o0 = KI(g*8), o1 = KI(g*8+4);
  const float* gamma = (tsel ? g2 : g1) + g*8;
  const float* beta  = (tsel ? b2 : b1) + g*8;

  float s = 0.f, ss = 0.f;
  #pragma unroll
  for (int ci = 0; ci < 8; ci++){
    const float4* row = (const float4*)(in + (size_t)ci*S);
    #pragma unroll
    for (int i = 0; i < 4; i++){
      float4 v = row[tid + i*256];
      s  += v.x + v.y + v.z + v.w;
      ss += v.x*v.x + v.y*v.y + v.z*v.z + v.w*v.w;
    }
  }
  #pragma unroll
  for (int off = 1; off < 64; off <<= 1){
    s  += __shfl_xor(s,  off);
    ss += __shfl_xor(ss, off);
  }
  __shared__ float red[8];
  __shared__ float mv[2];
  const int wave = tid >> 6, lane = tid & 63;
  if (lane == 0){ red[wave] = s; red[4+wave] = ss; }
  __syncthreads();
  if (tid == 0){
    float S1 = red[0]+red[1]+red[2]+red[3];
    float S2 = red[4]+red[5]+red[6]+red[7];
    const float invn = 1.0f/32768.0f;
    float mean = S1*invn;
    float var  = S2*invn - mean*mean;
    mv[0] = mean; mv[1] = rsqrtf(var + 1e-6f);
  }
  __syncthreads();
  const float mean = mv[0], rstd = mv[1];
  float sc[8], sh[8];
  #pragma unroll
  for (int ci = 0; ci < 8; ci++){ sc[ci] = rstd*gamma[ci]; sh[ci] = beta[ci] - mean*sc[ci]; }
  for (int i = 0; i < 16; i++){
    const int p = tid + i*256;
    ushort4 a0, a1;
    a0.x = f2bf(in[0*S+p]*sc[0]+sh[0]);
    a0.y = f2bf(in[1*S+p]*sc[1]+sh[1]);
    a0.z = f2bf(in[2*S+p]*sc[2]+sh[2]);
    a0.w = f2bf(in[3*S+p]*sc[3]+sh[3]);
    a1.x = f2bf(in[4*S+p]*sc[4]+sh[4]);
    a1.y = f2bf(in[5*S+p]*sc[5]+sh[5]);
    a1.z = f2bf(in[6*S+p]*sc[6]+sh[6]);
    a1.w = f2bf(in[7*S+p]*sc[7]+sh[7]);
    *(ushort4*)(outp + (size_t)p*CC + o0) = a0;
    *(ushort4*)(outp + (size_t)p*CC + o1) = a1;
  }
}

// ---------------- Q/K/V projection GEMMs (interleaved in & out) ----------------
__global__ __launch_bounds__(256) void qkv_gemm(unsigned short* __restrict__ ws,
    const float* __restrict__ bq, const float* __restrict__ bk, const float* __restrict__ bv)
{
  const int tid = threadIdx.x;
  const int lane = tid & 63, wave = tid >> 6;
  const int lq = lane & 15, lg = lane >> 4;
  const int bid = blockIdx.x;
  const int inst = bid >> 6, tile = bid & 63;
  const int which = inst % 3, b = inst / 3;
  int mblk, nblk;
  if (which == 2) { mblk = tile & 31; nblk = tile >> 5; }
  else            { mblk = tile >> 5; nblk = tile & 31; }
  const int mbase = mblk*128 + (wave>>1)*64;
  const int nbase = nblk*128 + (wave&1)*64;

  const unsigned short* Amat;
  const unsigned short* Bmat;
  if (which == 0)      { Amat = ws + OFF_WQ;                   Bmat = ws + OFF_NY + (size_t)b*S*CC; }
  else if (which == 1) { Amat = ws + OFF_WK;                   Bmat = ws + OFF_NX + (size_t)b*S*CC; }
  else                 { Amat = ws + OFF_NX + (size_t)b*S*CC;  Bmat = ws + OFF_WV; }

  f32x4 acc[4][4];
  #pragma unroll
  for (int i = 0; i < 4; i++)
    #pragma unroll
    for (int j = 0; j < 4; j++)
      acc[i][j] = (f32x4){0.f,0.f,0.f,0.f};

  const unsigned short* Arow = Amat + (size_t)(mbase + lq)*CC + lg*8;
  const unsigned short* Brow = Bmat + (size_t)(nbase + lq)*CC + lg*8;

  for (int ks = 0; ks < CC; ks += 32) {
    bf16x8 af[4], bfr[4];
    #pragma unroll
    for (int mt = 0; mt < 4; mt++)
      af[mt] = *(const bf16x8*)(Arow + (size_t)mt*16*CC + ks);
    #pragma unroll
    for (int nt = 0; nt < 4; nt++)
      bfr[nt] = *(const bf16x8*)(Brow + (size_t)nt*16*CC + ks);
    #pragma unroll
    for (int mt = 0; mt < 4; mt++)
      #pragma unroll
      for (int nt = 0; nt < 4; nt++)
        acc[mt][nt] = MFMA16(af[mt], bfr[nt], acc[mt][nt]);
  }

  if (which < 2) {
    const float* bias = (which==0) ? bq : bk;
    const float scl = (which==0) ? 0.125f*1.44269504089f : 1.0f;
    unsigned short* Outp = ws + (which==0 ? OFF_Q : OFF_K) + (size_t)b*HH*S*DD;
    #pragma unroll
    for (int mt = 0; mt < 4; mt++){
      const int o = mbase + mt*16 + lg*4;
      const float4 bb = *(const float4*)(bias + o);
      const int hd = o >> 6, db = KI(o & 63);
      #pragma unroll
      for (int nt = 0; nt < 4; nt++){
        const int p = nbase + nt*16 + lq;
        f32x4 v = acc[mt][nt];
        ushort4 r;
        r.x = f2bf((v[0]+bb.x)*scl); r.y = f2bf((v[1]+bb.y)*scl);
        r.z = f2bf((v[2]+bb.z)*scl); r.w = f2bf((v[3]+bb.w)*scl);
        *(ushort4*)(Outp + ((size_t)hd*S + p)*DD + db) = r;
      }
    }
  } else {
    unsigned short* Outp = ws + OFF_V + (size_t)b*CC*S;
    #pragma unroll
    for (int nt = 0; nt < 4; nt++){
      const int o = nbase + nt*16 + lq;
      const float bb = bv[o];
      #pragma unroll
      for (int mt = 0; mt < 4; mt++){
        const int p = mbase + mt*16 + lg*4;
        f32x4 v = acc[mt][nt];
        ushort4 r;
        r.x = f2bf(v[0]+bb); r.y = f2bf(v[1]+bb);
        r.z = f2bf(v[2]+bb); r.w = f2bf(v[3]+bb);
        *(ushort4*)(Outp + (size_t)o*S + KI(p)) = r;
      }
    }
  }
}

// ---------------- flash attention v4 ----------------
// 16 q per wave, 4 waves/block (64 q), grid = 64 qblk x 8 bh = 512 -> 2 blocks/CU.
// bh = bid&7: all 64 blocks of one (b,h) land on one XCD -> K/V L2-resident.
// LDS K/V tiles double-buffered, staged via global_load_lds (pre-swizzled source),
// fragments via XOR-swizzled ds_read_b128. Defer-max (THR=8) online softmax, exp2 domain.
__global__ __launch_bounds__(256, 2) void attn_k(unsigned short* __restrict__ ws)
{
  __shared__ __align__(1024) char lds[32768];   // K dbuf @0/8192, V dbuf @16384/24576
  const int tid = threadIdx.x;
  const int lane = tid & 63, wave = tid >> 6;
  const int lq = lane & 15, lg = lane >> 4;
  const int rsw = (lq & 7) << 4;
  const int bid = blockIdx.x;
  const int bh = bid & 7;                   // XCD-locality: same bh -> same XCD
  const int qblk = bid >> 3;                // 0..63
  const int b = bh >> 2, h = bh & 3;
  const unsigned short* Qp = ws + OFF_Q + (size_t)bh*S*DD;
  const unsigned short* Kp = ws + OFF_K + (size_t)bh*S*DD;
  const unsigned short* Vp = ws + OFF_V + ((size_t)b*CC + h*DD)*S;
  unsigned short* AOp = ws + OFF_AO + (size_t)b*S*CC;
  const int q = qblk*64 + wave*16 + lq;     // this lane's q column

  // Q fragment (interleaved layout -> two contiguous b128)
  bf16x8 qf[2];
  #pragma unroll
  for (int hh = 0; hh < 2; hh++)
    qf[hh] = *(const bf16x8*)(Qp + (size_t)q*DD + hh*32 + lg*8);

  // staging lane constants
  const int csel = ((lane & 7) ^ (lane >> 3)) * 8;   // pre-swizzled source chunk (elems)
  const int srow = wave*16 + (lane >> 3);            // tile row (+j*8)

  f32x4 acc[4];
  #pragma unroll
  for (int i = 0; i < 4; i++) acc[i] = (f32x4){0.f,0.f,0.f,0.f};
  float mr = -1e30f, lr = 0.f;

  // prologue: stage tile 0 into buf 0
  #pragma unroll
  for (int j = 0; j < 2; j++){
    const int row = srow + j*8;
    GLOAD_LDS16(Kp + (size_t)row*DD + csel,  lds + wave*2048 + j*1024);
    GLOAD_LDS16(Vp + (size_t)row*S  + csel,  lds + 16384 + wave*2048 + j*1024);
  }
  __syncthreads();

  int cur = 0;
  for (int t0 = 0; t0 < S; t0 += 64){
    const char* kb = lds + cur*8192;
    const char* vb = lds + 16384 + cur*8192;
    if (t0 + 64 < S){
      char* kn = lds + (cur^1)*8192;
      char* vn = lds + 16384 + (cur^1)*8192;
      #pragma unroll
      for (int j = 0; j < 2; j++){
        const int row = srow + j*8;
        GLOAD_LDS16(Kp + (size_t)(t0 + 64 + row)*DD + csel, kn + wave*2048 + j*1024);
        GLOAD_LDS16(Vp + (size_t)row*S + (t0 + 64) + csel,  vn + wave*2048 + j*1024);
      }
    }
    // K fragments + QK^T
    bf16x8 kf[4][2];
    #pragma unroll
    for (int mt = 0; mt < 4; mt++)
      #pragma unroll
      for (int hh = 0; hh < 2; hh++)
        kf[mt][hh] = *(const bf16x8*)(kb + mt*2048 + lq*128 + ((hh*64 + lg*16) ^ rsw));
    f32x4 st[4];
    #pragma unroll
    for (int mt = 0; mt < 4; mt++){
      f32x4 z = (f32x4){0.f,0.f,0.f,0.f};
      z = MFMA16(kf[mt][0], qf[0], z);
      z = MFMA16(kf[mt][1], qf[1], z);
      st[mt] = z;   // S^T[t0+mt*16+lg*4+r][q]
    }
    // V fragments (issued before softmax, consumed after)
    bf16x8 vf[4][2];
    #pragma unroll
    for (int dt = 0; dt < 4; dt++)
      #pragma unroll
      for (int th = 0; th < 2; th++)
        vf[dt][th] = *(const bf16x8*)(vb + dt*2048 + lq*128 + ((th*64 + lg*16) ^ rsw));
    // online softmax (exp2 domain) with defer-max
    float tm = fmaxf(fmaxf(fmaxf(st[0][0], st[0][1]), fmaxf(st[0][2], st[0][3])),
               fmaxf(fmaxf(fmaxf(st[1][0], st[1][1]), fmaxf(st[1][2], st[1][3])),
               fmaxf(fmaxf(fmaxf(st[2][0], st[2][1]), fmaxf(st[2][2], st[2][3])),
                     fmaxf(fmaxf(st[3][0], st[3][1]), fmaxf(st[3][2], st[3][3])))));
    tm = fmaxf(tm, __shfl_xor(tm, 16));
    tm = fmaxf(tm, __shfl_xor(tm, 32));
    const int defer = __all(tm <= mr + 8.f);
    if (!defer){
      const float mnew = fmaxf(mr, tm);
      const float c = __builtin_amdgcn_exp2f(mr - mnew);
      lr *= c;
      #pragma unroll
      for (int dt = 0; dt < 4; dt++)
        #pragma unroll
        for (int r = 0; r < 4; r++)
          acc[dt][r] *= c;
      mr = mnew;
    }
    float ts = 0.f;
    union PU { bf16x8 v; __bf16 e[8]; } p0, p1;
    #pragma unroll
    for (int mt = 0; mt < 4; mt++)
      #pragma unroll
      for (int r = 0; r < 4; r++){
        float e = __builtin_amdgcn_exp2f(st[mt][r] - mr);
        ts += e;
        if (mt < 2) p0.e[mt*4+r] = (__bf16)e;
        else        p1.e[(mt-2)*4+r] = (__bf16)e;
      }
    ts += __shfl_xor(ts, 16);
    ts += __shfl_xor(ts, 32);
    lr += ts;
    // PV
    #pragma unroll
    for (int dt = 0; dt < 4; dt++){
      f32x4 a = acc[dt];
      a = MFMA16(vf[dt][0], p0.v, a);
      a = MFMA16(vf[dt][1], p1.v, a);
      acc[dt] = a;
    }
    __syncthreads();   // staging for next tile complete; LDS reads consumed
    cur ^= 1;
  }

  const float inv = 1.0f / lr;
  #pragma unroll
  for (int dt = 0; dt < 4; dt++){
    f32x4 v;
    #pragma unroll
    for (int r = 0; r < 4; r++) v[r] = acc[dt][r] * inv;
    *(ushort4*)(AOp + (size_t)q*CC + KI(h*64 + dt*16 + lg*4)) = pk4(v);
  }
}

// ---------------- output projection + residual ----------------
__global__ __launch_bounds__(256) void outproj_k(const unsigned short* __restrict__ ws,
    const float* __restrict__ bo, const float* __restrict__ x, float* __restrict__ out)
{
  const int tid = threadIdx.x;
  const int lane = tid & 63, wave = tid >> 6;
  const int lq = lane & 15, lg = lane >> 4;
  const int bid = blockIdx.x;
  const int b = bid >> 6;
  const int tile = bid & 63;
  const int mblk = tile & 31, nblk = tile >> 5;
  const int mbase = mblk*128 + (wave>>1)*64;
  const int nbase = nblk*128 + (wave&1)*64;
  const unsigned short* Amat = ws + OFF_AO + (size_t)b*S*CC;
  const unsigned short* Bmat = ws + OFF_WO;

  f32x4 acc[4][4];
  #pragma unroll
  for (int i = 0; i < 4; i++)
    #pragma unroll
    for (int j = 0; j < 4; j++)
      acc[i][j] = (f32x4){0.f,0.f,0.f,0.f};

  const unsigned short* Arow = Amat + (size_t)(mbase + lq)*CC + lg*8;
  const unsigned short* Brow = Bmat + (size_t)(nbase + lq)*CC + lg*8;
  for (int ks = 0; ks < CC; ks += 32) {
    bf16x8 af[4], bfr[4];
    #pragma unroll
    for (int mt = 0; mt < 4; mt++)
      af[mt] = *(const bf16x8*)(Arow + (size_t)mt*16*CC + ks);
    #pragma unroll
    for (int nt = 0; nt < 4; nt++)
      bfr[nt] = *(const bf16x8*)(Brow + (size_t)nt*16*CC + ks);
    #pragma unroll
    for (int mt = 0; mt < 4; mt++)
      #pragma unroll
      for (int nt = 0; nt < 4; nt++)
        acc[mt][nt] = MFMA16(af[mt], bfr[nt], acc[mt][nt]);
  }
  #pragma unroll
  for (int nt = 0; nt < 4; nt++){
    const int o = nbase + nt*16 + lq;
    const float bb = bo[o];
    #pragma unroll
    for (int mt = 0; mt < 4; mt++){
      const int p = mbase + mt*16 + lg*4;
      const size_t idx = ((size_t)b*CC + o)*S + p;
      const float4 xr = *(const float4*)(x + idx);
      f32x4 v = acc[mt][nt];
      float4 r; r.x = v[0]+bb+xr.x; r.y = v[1]+bb+xr.y; r.z = v[2]+bb+xr.z; r.w = v[3]+bb+xr.w;
      *(float4*)(out + idx) = r;
    }
  }
}

extern "C" void kernel_launch(void* const* d_in, const int* in_sizes, int n_in,
                              void* d_out, int out_size, void* d_ws, size_t ws_size,
                              hipStream_t stream) {
  const float* x  = (const float*)d_in[0];
  const float* y  = (const float*)d_in[1];
  const float* g1 = (const float*)d_in[2];
  const float* b1 = (const float*)d_in[3];
  const float* g2 = (const float*)d_in[4];
  const float* b2 = (const float*)d_in[5];
  const float* wq = (const float*)d_in[6];
  const float* bq = (const float*)d_in[7];
  const float* wk = (const float*)d_in[8];
  const float* bk = (const float*)d_in[9];
  const float* wv = (const float*)d_in[10];
  const float* bv = (const float*)d_in[11];
  const float* wo = (const float*)d_in[12];
  const float* bo = (const float*)d_in[13];
  float* out = (float*)d_out;
  unsigned short* ws16 = (unsigned short*)d_ws;

  convert_w  <<<256, 256, 0, stream>>>(wq, wk, wv, wo, ws16);
  groupnorm_k<<<128, 256, 0, stream>>>(x, y, g1, b1, g2, b2, ws16);
  qkv_gemm   <<<384, 256, 0, stream>>>(ws16, bq, bk, bv);
  attn_k     <<<512, 256, 0, stream>>>(ws16);
  outproj_k  <<<128, 256, 0, stream>>>(ws16, bo, x, out);
}

// Round 5
// 121.251 us; speedup vs baseline: 4.5033x; 1.1633x over previous
//
#include <hip/hip_runtime.h>

typedef __bf16 bf16_t;
typedef bf16_t bf16x8 __attribute__((ext_vector_type(8)));
typedef float f32x4 __attribute__((ext_vector_type(4)));

#define MFMA16(a,b,c) __builtin_amdgcn_mfma_f32_16x16x32_bf16((a),(b),(c),0,0,0)

#define GLOAD_LDS16(gsrc, ldst) \
  __builtin_amdgcn_global_load_lds((const __attribute__((address_space(1))) unsigned int*)(gsrc), \
                                   (__attribute__((address_space(3))) unsigned int*)(ldst), 16, 0, 0)

__device__ __forceinline__ unsigned short f2bf(float f){
  unsigned int u = __builtin_bit_cast(unsigned int, f);
  u = (u + 0x7FFFu + ((u >> 16) & 1u)) >> 16;
  return (unsigned short)u;
}
__device__ __forceinline__ ushort4 pk4(f32x4 v){
  union { __bf16 b[4]; ushort4 u; } r;
  r.b[0]=(__bf16)v[0]; r.b[1]=(__bf16)v[1]; r.b[2]=(__bf16)v[2]; r.b[3]=(__bf16)v[3];
  return r.u;
}

// KI: k-interleave within 64-elem segment (for Q/K/V consumed by attention).
__device__ __forceinline__ int KI(int d){   // d 4-aligned
  int gi = (d >> 2) & 15;
  int pos = (gi & 8) | ((gi & 3) << 1) | ((gi >> 2) & 1);
  return (d & ~63) | (pos << 2);
}

// Blocked fragment layout for GEMM operands [R][Kt] (Kt=256 here):
// idx(r,c) = (r>>4)*Kt*16 + (c>>5)*512 + (r&15)*32 + ((c&15)>>2)*8 + ((c>>4)&1)*4 + (c&3)
// Wave fragment load (rowbase 16-aligned, ks 32-aligned):
//   addr = T + rowbase*Kt + ks*16 + (lq*32 + lg*8)   -> contiguous 1KB per wave.
__device__ __forceinline__ int BL256(int r, int c){
  return ((r >> 4) << 12) + (((c >> 5)) << 9) + ((r & 15) << 5)
       + (((c & 15) >> 2) << 3) + (((c >> 4) & 1) << 2) + (c & 3);
}

constexpr int BN = 2;
constexpr int CC = 256;
constexpr int S  = 4096;
constexpr int HH = 4;
constexpr int DD = 64;

constexpr size_t OFF_WQ = 0;
constexpr size_t OFF_WK = 65536;
constexpr size_t OFF_WV = 131072;
constexpr size_t OFF_WO = 196608;
constexpr size_t OFF_NY = 262144;                      // blocked [p][c]
constexpr size_t OFF_NX = OFF_NY + (size_t)BN*S*CC;    // blocked [p][c]
constexpr size_t OFF_Q  = OFF_NX + (size_t)BN*S*CC;    // [b][h][p][d~KI] (pre-scaled 0.125*log2e)
constexpr size_t OFF_K  = OFF_Q  + (size_t)BN*S*CC;    // [b][h][p][d~KI]
constexpr size_t OFF_V  = OFF_K  + (size_t)BN*S*CC;    // [b][c][p~KI]
constexpr size_t OFF_AO = OFF_V  + (size_t)BN*S*CC;    // blocked [p][c]

// ---------------- weight fp32 -> bf16 (blocked) ----------------
__global__ __launch_bounds__(256) void convert_w(const float* __restrict__ wq, const float* __restrict__ wk,
    const float* __restrict__ wv, const float* __restrict__ wo, unsigned short* __restrict__ ws)
{
  const int idx = blockIdx.x*256 + threadIdx.x;
  const int m = idx >> 14;
  const int off = (idx & 16383) << 2;          // 4-aligned elem in [o][c]
  const float* src = (m==0) ? wq : (m==1) ? wk : (m==2) ? wv : wo;
  float4 v = *(const float4*)(src + off);
  ushort4 r; r.x=f2bf(v.x); r.y=f2bf(v.y); r.z=f2bf(v.z); r.w=f2bf(v.w);
  const int o = off >> 8, c = off & 255;
  *(ushort4*)(ws + (size_t)m*65536 + BL256(o, c)) = r;
}

// ---------------- GroupNorm -> blocked [p][c] bf16 ----------------
__global__ __launch_bounds__(256) void groupnorm_k(const float* __restrict__ x, const float* __restrict__ y,
    const float* __restrict__ g1, const float* __restrict__ b1,
    const float* __restrict__ g2, const float* __restrict__ b2,
    unsigned short* __restrict__ ws)
{
  const int tid = threadIdx.x;
  const int bid = blockIdx.x;
  const int tsel = bid >> 6;
  const int rem  = bid & 63;
  const int b = rem >> 5, g = rem & 31;
  const float* in = (tsel ? y : x) + ((size_t)b*CC + g*8)*S;
  unsigned short* outp = ws + (tsel ? OFF_NY : OFF_NX) + (size_t)b*S*CC;
  const int j = g & 3;
  const int gk = (g >> 2) * 512;
  const int posA = (j & 1)*16 + (j >> 1)*4;   // glob 2j
  const int posB = posA + 8;                  // glob 2j+1
  const float* gamma = (tsel ? g2 : g1) + g*8;
  const float* beta  = (tsel ? b2 : b1) + g*8;

  float s = 0.f, ss = 0.f;
  #pragma unroll
  for (int ci = 0; ci < 8; ci++){
    const float4* row = (const float4*)(in + (size_t)ci*S);
    #pragma unroll
    for (int i = 0; i < 4; i++){
      float4 v = row[tid + i*256];
      s  += v.x + v.y + v.z + v.w;
      ss += v.x*v.x + v.y*v.y + v.z*v.z + v.w*v.w;
    }
  }
  #pragma unroll
  for (int off = 1; off < 64; off <<= 1){
    s  += __shfl_xor(s,  off);
    ss += __shfl_xor(ss, off);
  }
  __shared__ float red[8];
  __shared__ float mv[2];
  const int wave = tid >> 6, lane = tid & 63;
  if (lane == 0){ red[wave] = s; red[4+wave] = ss; }
  __syncthreads();
  if (tid == 0){
    float S1 = red[0]+red[1]+red[2]+red[3];
    float S2 = red[4]+red[5]+red[6]+red[7];
    const float invn = 1.0f/32768.0f;
    float mean = S1*invn;
    float var  = S2*invn - mean*mean;
    mv[0] = mean; mv[1] = rsqrtf(var + 1e-6f);
  }
  __syncthreads();
  const float mean = mv[0], rstd = mv[1];
  float sc[8], sh[8];
  #pragma unroll
  for (int ci = 0; ci < 8; ci++){ sc[ci] = rstd*gamma[ci]; sh[ci] = beta[ci] - mean*sc[ci]; }
  for (int i = 0; i < 16; i++){
    const int p = tid + i*256;
    const int base = ((p >> 4) << 12) + gk + ((p & 15) << 5);
    ushort4 a0, a1;
    a0.x = f2bf(in[0*S+p]*sc[0]+sh[0]);
    a0.y = f2bf(in[1*S+p]*sc[1]+sh[1]);
    a0.z = f2bf(in[2*S+p]*sc[2]+sh[2]);
    a0.w = f2bf(in[3*S+p]*sc[3]+sh[3]);
    a1.x = f2bf(in[4*S+p]*sc[4]+sh[4]);
    a1.y = f2bf(in[5*S+p]*sc[5]+sh[5]);
    a1.z = f2bf(in[6*S+p]*sc[6]+sh[6]);
    a1.w = f2bf(in[7*S+p]*sc[7]+sh[7]);
    *(ushort4*)(outp + base + posA) = a0;
    *(ushort4*)(outp + base + posB) = a1;
  }
}

// ---------------- Q/K/V projection GEMMs (blocked frag loads) ----------------
__global__ __launch_bounds__(256) void qkv_gemm(unsigned short* __restrict__ ws,
    const float* __restrict__ bq, const float* __restrict__ bk, const float* __restrict__ bv)
{
  const int tid = threadIdx.x;
  const int lane = tid & 63, wave = tid >> 6;
  const int lq = lane & 15, lg = lane >> 4;
  const int lofs = lq*32 + lg*8;               // within-fragment lane offset (elems)
  const int bid = blockIdx.x;
  const int inst = bid >> 6, tile = bid & 63;
  const int which = inst % 3, b = inst / 3;
  int mblk, nblk;
  if (which == 2) { mblk = tile & 31; nblk = tile >> 5; }
  else            { mblk = tile >> 5; nblk = tile & 31; }
  const int mbase = mblk*128 + (wave>>1)*64;
  const int nbase = nblk*128 + (wave&1)*64;

  const unsigned short* Amat;
  const unsigned short* Bmat;
  if (which == 0)      { Amat = ws + OFF_WQ;                   Bmat = ws + OFF_NY + (size_t)b*S*CC; }
  else if (which == 1) { Amat = ws + OFF_WK;                   Bmat = ws + OFF_NX + (size_t)b*S*CC; }
  else                 { Amat = ws + OFF_NX + (size_t)b*S*CC;  Bmat = ws + OFF_WV; }

  f32x4 acc[4][4];
  #pragma unroll
  for (int i = 0; i < 4; i++)
    #pragma unroll
    for (int j = 0; j < 4; j++)
      acc[i][j] = (f32x4){0.f,0.f,0.f,0.f};

  const unsigned short* Arow = Amat + (size_t)mbase*CC + lofs;
  const unsigned short* Brow = Bmat + (size_t)nbase*CC + lofs;

  for (int ks = 0; ks < CC; ks += 32) {
    bf16x8 af[4], bfr[4];
    #pragma unroll
    for (int mt = 0; mt < 4; mt++)
      af[mt] = *(const bf16x8*)(Arow + mt*16*CC + ks*16);
    #pragma unroll
    for (int nt = 0; nt < 4; nt++)
      bfr[nt] = *(const bf16x8*)(Brow + nt*16*CC + ks*16);
    #pragma unroll
    for (int mt = 0; mt < 4; mt++)
      #pragma unroll
      for (int nt = 0; nt < 4; nt++)
        acc[mt][nt] = MFMA16(af[mt], bfr[nt], acc[mt][nt]);
  }

  if (which < 2) {
    const float* bias = (which==0) ? bq : bk;
    const float scl = (which==0) ? 0.125f*1.44269504089f : 1.0f;
    unsigned short* Outp = ws + (which==0 ? OFF_Q : OFF_K) + (size_t)b*HH*S*DD;
    #pragma unroll
    for (int mt = 0; mt < 4; mt++){
      const int o = mbase + mt*16 + lg*4;
      const float4 bb = *(const float4*)(bias + o);
      const int hd = o >> 6, db = KI(o & 63);
      #pragma unroll
      for (int nt = 0; nt < 4; nt++){
        const int p = nbase + nt*16 + lq;
        f32x4 v = acc[mt][nt];
        ushort4 r;
        r.x = f2bf((v[0]+bb.x)*scl); r.y = f2bf((v[1]+bb.y)*scl);
        r.z = f2bf((v[2]+bb.z)*scl); r.w = f2bf((v[3]+bb.w)*scl);
        *(ushort4*)(Outp + ((size_t)hd*S + p)*DD + db) = r;
      }
    }
  } else {
    unsigned short* Outp = ws + OFF_V + (size_t)b*CC*S;
    #pragma unroll
    for (int nt = 0; nt < 4; nt++){
      const int o = nbase + nt*16 + lq;
      const float bb = bv[o];
      #pragma unroll
      for (int mt = 0; mt < 4; mt++){
        const int p = mbase + mt*16 + lg*4;
        f32x4 v = acc[mt][nt];
        ushort4 r;
        r.x = f2bf(v[0]+bb); r.y = f2bf(v[1]+bb);
        r.z = f2bf(v[2]+bb); r.w = f2bf(v[3]+bb);
        *(ushort4*)(Outp + (size_t)o*S + KI(p)) = r;
      }
    }
  }
}

// ---------------- flash attention v5 ----------------
// 16 q/wave, 4 waves (64 q), grid 512 (bh=bid&7 -> XCD-local), 2 blocks/CU.
// KVBLK=128: one barrier pair per 128 t. Compile-time double-buffer (template) ->
// all ds_reads are base-reg+immediate. Defer-max online softmax, exp2 domain.
// LDS: K0@0 K1@16384 V0@32768 V1@49152 (64KB).
template<int KB, int VB, int KN, int VN>
__device__ __forceinline__ void attn_body(char* lds,
    const unsigned short* __restrict__ Kp, const unsigned short* __restrict__ Vp,
    int t0, bool stage, size_t kSrcOfs, size_t vSrcE, size_t vSrcO, int wave,
    int kofs0, int kofs1, int vofs0, int vofs1,
    bf16x8 qf0, bf16x8 qf1, f32x4 (&acc)[4], float& mr, float& lr)
{
  if (stage){
    const unsigned short* ksrc = Kp + (size_t)(t0+128)*DD + kSrcOfs;
    char* kd = lds + KN + wave*4096;
    GLOAD_LDS16(ksrc,        kd);
    GLOAD_LDS16(ksrc +  512, kd + 1024);
    GLOAD_LDS16(ksrc + 1024, kd + 2048);
    GLOAD_LDS16(ksrc + 1536, kd + 3072);
    const unsigned short* vsrc = Vp + (t0+128);
    char* vd = lds + VN + wave*4096;
    GLOAD_LDS16(vsrc + vSrcE,         vd);
    GLOAD_LDS16(vsrc + vSrcO + 16384, vd + 1024);
    GLOAD_LDS16(vsrc + vSrcE + 32768, vd + 2048);
    GLOAD_LDS16(vsrc + vSrcO + 49152, vd + 3072);
  }
  #pragma unroll
  for (int st = 0; st < 2; st++){
    // K frags + QK^T
    bf16x8 kf[4][2];
    #pragma unroll
    for (int mt = 0; mt < 4; mt++){
      kf[mt][0] = *(const bf16x8*)(lds + KB + st*8192 + mt*2048 + kofs0);
      kf[mt][1] = *(const bf16x8*)(lds + KB + st*8192 + mt*2048 + kofs1);
    }
    f32x4 stt[4];
    #pragma unroll
    for (int mt = 0; mt < 4; mt++){
      f32x4 z = (f32x4){0.f,0.f,0.f,0.f};
      z = MFMA16(kf[mt][0], qf0, z);
      z = MFMA16(kf[mt][1], qf1, z);
      stt[mt] = z;
    }
    // V frags (issued before softmax)
    bf16x8 vf[4][2];
    #pragma unroll
    for (int dt = 0; dt < 4; dt++){
      vf[dt][0] = *(const bf16x8*)(lds + VB + dt*4096 + st*128 + vofs0);
      vf[dt][1] = *(const bf16x8*)(lds + VB + dt*4096 + st*128 + vofs1);
    }
    // softmax (exp2 domain), defer-max THR=8
    float tm = fmaxf(
        fmaxf(fmaxf(fmaxf(stt[0][0], stt[0][1]), stt[0][2]), fmaxf(fmaxf(stt[0][3], stt[1][0]), stt[1][1])),
        fmaxf(fmaxf(fmaxf(stt[1][2], stt[1][3]), fmaxf(stt[2][0], stt[2][1])),
              fmaxf(fmaxf(stt[2][2], stt[2][3]), fmaxf(fmaxf(stt[3][0], stt[3][1]), fmaxf(stt[3][2], stt[3][3])))));
    tm = fmaxf(tm, __shfl_xor(tm, 16));
    tm = fmaxf(tm, __shfl_xor(tm, 32));
    if (!__all(tm <= mr + 8.f)){
      const float mnew = fmaxf(mr, tm);
      const float c = __builtin_amdgcn_exp2f(mr - mnew);
      lr *= c;
      #pragma unroll
      for (int dt = 0; dt < 4; dt++)
        #pragma unroll
        for (int r = 0; r < 4; r++)
          acc[dt][r] *= c;
      mr = mnew;
    }
    float ts = 0.f;
    union PU { bf16x8 v; __bf16 e[8]; } p0, p1;
    #pragma unroll
    for (int mt = 0; mt < 4; mt++)
      #pragma unroll
      for (int r = 0; r < 4; r++){
        float e = __builtin_amdgcn_exp2f(stt[mt][r] - mr);
        ts += e;
        if (mt < 2) p0.e[mt*4+r] = (__bf16)e;
        else        p1.e[(mt-2)*4+r] = (__bf16)e;
      }
    ts += __shfl_xor(ts, 16);
    ts += __shfl_xor(ts, 32);
    lr += ts;
    #pragma unroll
    for (int dt = 0; dt < 4; dt++){
      f32x4 a = acc[dt];
      a = MFMA16(vf[dt][0], p0.v, a);
      a = MFMA16(vf[dt][1], p1.v, a);
      acc[dt] = a;
    }
  }
}

__global__ __launch_bounds__(256, 2) void attn_k(unsigned short* __restrict__ ws)
{
  __shared__ __align__(1024) char lds[65536];
  const int tid = threadIdx.x;
  const int lane = tid & 63, wave = tid >> 6;
  const int lq = lane & 15, lg = lane >> 4;
  const int rsw = (lq & 7) << 4;
  const int bid = blockIdx.x;
  const int bh = bid & 7;
  const int qblk = bid >> 3;
  const int b = bh >> 2, h = bh & 3;
  const unsigned short* Qp = ws + OFF_Q + (size_t)bh*S*DD;
  const unsigned short* Kp = ws + OFF_K + (size_t)bh*S*DD;
  const unsigned short* Vp = ws + OFF_V + ((size_t)b*CC + h*DD)*S;
  unsigned short* AOp = ws + OFF_AO + (size_t)b*S*CC;
  const int q = qblk*64 + wave*16 + lq;

  bf16x8 qf0 = *(const bf16x8*)(Qp + (size_t)q*DD + lg*8);
  bf16x8 qf1 = *(const bf16x8*)(Qp + (size_t)q*DD + 32 + lg*8);

  // ds_read per-lane byte offsets (constant across loop)
  const int kofs0 = lq*128 + ((lg*16) ^ rsw);
  const int kofs1 = kofs0 ^ 64;
  const int vofs0 = lq*256 + ((lg*16) ^ rsw);
  const int vofs1 = vofs0 ^ 64;

  // staging per-lane source offsets (elems)
  const int csK = ((lane & 7) ^ ((lane >> 3) & 7)) * 8;
  const size_t kSrcOfs = (size_t)(wave*32 + (lane >> 3))*DD + csK;
  const int ceV = ((lane & 15) ^ (lane >> 4)) * 8;
  const size_t vRow = (size_t)(wave*16 + (lane >> 4))*S;
  const size_t vSrcE = vRow + ceV;
  const size_t vSrcO = vRow + (ceV ^ 32);

  f32x4 acc[4];
  #pragma unroll
  for (int i = 0; i < 4; i++) acc[i] = (f32x4){0.f,0.f,0.f,0.f};
  float mr = -1e30f, lr = 0.f;

  // prologue: stage t=0..128 into buf0
  {
    const unsigned short* ksrc = Kp + kSrcOfs;
    char* kd = lds + wave*4096;
    GLOAD_LDS16(ksrc,        kd);
    GLOAD_LDS16(ksrc +  512, kd + 1024);
    GLOAD_LDS16(ksrc + 1024, kd + 2048);
    GLOAD_LDS16(ksrc + 1536, kd + 3072);
    char* vd = lds + 32768 + wave*4096;
    GLOAD_LDS16(Vp + vSrcE,         vd);
    GLOAD_LDS16(Vp + vSrcO + 16384, vd + 1024);
    GLOAD_LDS16(Vp + vSrcE + 32768, vd + 2048);
    GLOAD_LDS16(Vp + vSrcO + 49152, vd + 3072);
  }
  __syncthreads();

  for (int t0 = 0; t0 < S; t0 += 256){
    attn_body<0, 32768, 16384, 49152>(lds, Kp, Vp, t0, true,
        kSrcOfs, vSrcE, vSrcO, wave, kofs0, kofs1, vofs0, vofs1, qf0, qf1, acc, mr, lr);
    __syncthreads();
    attn_body<16384, 49152, 0, 32768>(lds, Kp, Vp, t0+128, (t0+256) < S,
        kSrcOfs, vSrcE, vSrcO, wave, kofs0, kofs1, vofs0, vofs1, qf0, qf1, acc, mr, lr);
    __syncthreads();
  }

  const float inv = 1.0f / lr;
  const int aobase = ((q >> 4) << 12) + ((q & 15) << 5);
  #pragma unroll
  for (int dt = 0; dt < 4; dt++){
    f32x4 v;
    #pragma unroll
    for (int r = 0; r < 4; r++) v[r] = acc[dt][r] * inv;
    const int idx = aobase + (h*2 + (dt >> 1))*512 + lg*8 + (dt & 1)*4;
    *(ushort4*)(AOp + idx) = pk4(v);
  }
}

// ---------------- output projection + residual (64x128 tiles, 256 blocks) ----------------
__global__ __launch_bounds__(256) void outproj_k(const unsigned short* __restrict__ ws,
    const float* __restrict__ bo, const float* __restrict__ x, float* __restrict__ out)
{
  const int tid = threadIdx.x;
  const int lane = tid & 63, wave = tid >> 6;
  const int lq = lane & 15, lg = lane >> 4;
  const int lofs = lq*32 + lg*8;
  const int bid = blockIdx.x;
  const int b = bid >> 7;
  const int tile = bid & 127;
  const int mtile = tile >> 1, ntile = tile & 1;
  const int mbase = mtile*64 + wave*16;       // p rows (16 per wave)
  const int nbase = ntile*128;                // o cols
  const unsigned short* Amat = ws + OFF_AO + (size_t)b*S*CC;   // blocked [p][c]
  const unsigned short* Bmat = ws + OFF_WO;                    // blocked [o][c]

  f32x4 acc[8];
  #pragma unroll
  for (int i = 0; i < 8; i++) acc[i] = (f32x4){0.f,0.f,0.f,0.f};

  const unsigned short* Arow = Amat + (size_t)mbase*CC + lofs;
  const unsigned short* Brow = Bmat + (size_t)nbase*CC + lofs;
  for (int ks = 0; ks < CC; ks += 32) {
    bf16x8 af = *(const bf16x8*)(Arow + ks*16);
    bf16x8 bfr[8];
    #pragma unroll
    for (int nt = 0; nt < 8; nt++)
      bfr[nt] = *(const bf16x8*)(Brow + nt*16*CC + ks*16);
    #pragma unroll
    for (int nt = 0; nt < 8; nt++)
      acc[nt] = MFMA16(af, bfr[nt], acc[nt]);
  }
  #pragma unroll
  for (int nt = 0; nt < 8; nt++){
    const int o = nbase + nt*16 + lq;
    const float bb = bo[o];
    const int p = mbase + lg*4;
    const size_t idx = ((size_t)b*CC + o)*S + p;
    const float4 xr = *(const float4*)(x + idx);
    f32x4 v = acc[nt];
    float4 r; r.x = v[0]+bb+xr.x; r.y = v[1]+bb+xr.y; r.z = v[2]+bb+xr.z; r.w = v[3]+bb+xr.w;
    *(float4*)(out + idx) = r;
  }
}

extern "C" void kernel_launch(void* const* d_in, const int* in_sizes, int n_in,
                              void* d_out, int out_size, void* d_ws, size_t ws_size,
                              hipStream_t stream) {
  const float* x  = (const float*)d_in[0];
  const float* y  = (const float*)d_in[1];
  const float* g1 = (const float*)d_in[2];
  const float* b1 = (const float*)d_in[3];
  const float* g2 = (const float*)d_in[4];
  const float* b2 = (const float*)d_in[5];
  const float* wq = (const float*)d_in[6];
  const float* bq = (const float*)d_in[7];
  const float* wk = (const float*)d_in[8];
  const float* bk = (const float*)d_in[9];
  const float* wv = (const float*)d_in[10];
  const float* bv = (const float*)d_in[11];
  const float* wo = (const float*)d_in[12];
  const float* bo = (const float*)d_in[13];
  float* out = (float*)d_out;
  unsigned short* ws16 = (unsigned short*)d_ws;

  convert_w  <<<256, 256, 0, stream>>>(wq, wk, wv, wo, ws16);
  groupnorm_k<<<128, 256, 0, stream>>>(x, y, g1, b1, g2, b2, ws16);
  qkv_gemm   <<<384, 256, 0, stream>>>(ws16, bq, bk, bv);
  attn_k     <<<512, 256, 0, stream>>>(ws16);
  outproj_k  <<<256, 256, 0, stream>>>(ws16, bo, x, out);
}

// Round 6
// 118.147 us; speedup vs baseline: 4.6216x; 1.0263x over previous
//
#include <hip/hip_runtime.h>

typedef __bf16 bf16_t;
typedef bf16_t bf16x8 __attribute__((ext_vector_type(8)));
typedef float f32x4 __attribute__((ext_vector_type(4)));

#define MFMA16(a,b,c) __builtin_amdgcn_mfma_f32_16x16x32_bf16((a),(b),(c),0,0,0)

#define GLOAD_LDS16(gsrc, ldst) \
  __builtin_amdgcn_global_load_lds((const __attribute__((address_space(1))) unsigned int*)(gsrc), \
                                   (__attribute__((address_space(3))) unsigned int*)(ldst), 16, 0, 0)

__device__ __forceinline__ unsigned short f2bf(float f){
  unsigned int u = __builtin_bit_cast(unsigned int, f);
  u = (u + 0x7FFFu + ((u >> 16) & 1u)) >> 16;
  return (unsigned short)u;
}
__device__ __forceinline__ float bf2f(unsigned short u){
  return __builtin_bit_cast(float, (unsigned int)u << 16);
}
__device__ __forceinline__ ushort4 pk4(f32x4 v){
  union { __bf16 b[4]; ushort4 u; } r;
  r.b[0]=(__bf16)v[0]; r.b[1]=(__bf16)v[1]; r.b[2]=(__bf16)v[2]; r.b[3]=(__bf16)v[3];
  return r.u;
}

// KI: k-interleave within 64-elem segment (for Q/K/V consumed by attention).
__device__ __forceinline__ int KI(int d){   // d 4-aligned
  int gi = (d >> 2) & 15;
  int pos = (gi & 8) | ((gi & 3) << 1) | ((gi >> 2) & 1);
  return (d & ~63) | (pos << 2);
}

// Blocked fragment layout for GEMM operands [R][256]:
// wave fragment load at (rowbase*256 + ks*16 + lq*32 + lg*8) is contiguous 1KB.
__device__ __forceinline__ int BL256(int r, int c){
  return ((r >> 4) << 12) + (((c >> 5)) << 9) + ((r & 15) << 5)
       + (((c & 15) >> 2) << 3) + (((c >> 4) & 1) << 2) + (c & 3);
}

constexpr int BN = 2;
constexpr int CC = 256;
constexpr int S  = 4096;
constexpr int HH = 4;
constexpr int DD = 64;

constexpr size_t OFF_WQ = 0;
constexpr size_t OFF_WK = 65536;
constexpr size_t OFF_WV = 131072;
constexpr size_t OFF_WO = 196608;
constexpr size_t OFF_NY = 262144;                      // blocked [p][c]
constexpr size_t OFF_NX = OFF_NY + (size_t)BN*S*CC;    // blocked [p][c]
constexpr size_t OFF_Q  = OFF_NX + (size_t)BN*S*CC;    // [b][h][p][d~KI] (pre-scaled 0.125*log2e)
constexpr size_t OFF_K  = OFF_Q  + (size_t)BN*S*CC;    // [b][h][p][d~KI]
constexpr size_t OFF_V  = OFF_K  + (size_t)BN*S*CC;    // [b][c][p~KI]
constexpr size_t OFF_AO = OFF_V  + (size_t)BN*S*CC;    // blocked [p][c]
// attention partials overlay the (dead-by-then) NX/NY region:
constexpr size_t OFF_PACC = OFF_NY;                    // [ch][bh][q][d] bf16: 2*8*4096*64 = 4,194,304 ush
constexpr size_t OFF_ML   = OFF_NY + 4194304;          // [ch][bh][q][2] f32: 262,144 ush

// ---------------- weight fp32 -> bf16 (blocked) ----------------
__global__ __launch_bounds__(256) void convert_w(const float* __restrict__ wq, const float* __restrict__ wk,
    const float* __restrict__ wv, const float* __restrict__ wo, unsigned short* __restrict__ ws)
{
  const int idx = blockIdx.x*256 + threadIdx.x;
  const int m = idx >> 14;
  const int off = (idx & 16383) << 2;          // 4-aligned elem in [o][c]
  const float* src = (m==0) ? wq : (m==1) ? wk : (m==2) ? wv : wo;
  float4 v = *(const float4*)(src + off);
  ushort4 r; r.x=f2bf(v.x); r.y=f2bf(v.y); r.z=f2bf(v.z); r.w=f2bf(v.w);
  const int o = off >> 8, c = off & 255;
  *(ushort4*)(ws + (size_t)m*65536 + BL256(o, c)) = r;
}

// ---------------- GroupNorm -> blocked [p][c] bf16 ----------------
__global__ __launch_bounds__(256) void groupnorm_k(const float* __restrict__ x, const float* __restrict__ y,
    const float* __restrict__ g1, const float* __restrict__ b1,
    const float* __restrict__ g2, const float* __restrict__ b2,
    unsigned short* __restrict__ ws)
{
  const int tid = threadIdx.x;
  const int bid = blockIdx.x;
  const int tsel = bid >> 6;
  const int rem  = bid & 63;
  const int b = rem >> 5, g = rem & 31;
  const float* in = (tsel ? y : x) + ((size_t)b*CC + g*8)*S;
  unsigned short* outp = ws + (tsel ? OFF_NY : OFF_NX) + (size_t)b*S*CC;
  const int j = g & 3;
  const int gk = (g >> 2) * 512;
  const int posA = (j & 1)*16 + (j >> 1)*4;
  const int posB = posA + 8;
  const float* gamma = (tsel ? g2 : g1) + g*8;
  const float* beta  = (tsel ? b2 : b1) + g*8;

  float s = 0.f, ss = 0.f;
  #pragma unroll
  for (int ci = 0; ci < 8; ci++){
    const float4* row = (const float4*)(in + (size_t)ci*S);
    #pragma unroll
    for (int i = 0; i < 4; i++){
      float4 v = row[tid + i*256];
      s  += v.x + v.y + v.z + v.w;
      ss += v.x*v.x + v.y*v.y + v.z*v.z + v.w*v.w;
    }
  }
  #pragma unroll
  for (int off = 1; off < 64; off <<= 1){
    s  += __shfl_xor(s,  off);
    ss += __shfl_xor(ss, off);
  }
  __shared__ float red[8];
  __shared__ float mv[2];
  const int wave = tid >> 6, lane = tid & 63;
  if (lane == 0){ red[wave] = s; red[4+wave] = ss; }
  __syncthreads();
  if (tid == 0){
    float S1 = red[0]+red[1]+red[2]+red[3];
    float S2 = red[4]+red[5]+red[6]+red[7];
    const float invn = 1.0f/32768.0f;
    float mean = S1*invn;
    float var  = S2*invn - mean*mean;
    mv[0] = mean; mv[1] = rsqrtf(var + 1e-6f);
  }
  __syncthreads();
  const float mean = mv[0], rstd = mv[1];
  float sc[8], sh[8];
  #pragma unroll
  for (int ci = 0; ci < 8; ci++){ sc[ci] = rstd*gamma[ci]; sh[ci] = beta[ci] - mean*sc[ci]; }
  for (int i = 0; i < 16; i++){
    const int p = tid + i*256;
    const int base = ((p >> 4) << 12) + gk + ((p & 15) << 5);
    ushort4 a0, a1;
    a0.x = f2bf(in[0*S+p]*sc[0]+sh[0]);
    a0.y = f2bf(in[1*S+p]*sc[1]+sh[1]);
    a0.z = f2bf(in[2*S+p]*sc[2]+sh[2]);
    a0.w = f2bf(in[3*S+p]*sc[3]+sh[3]);
    a1.x = f2bf(in[4*S+p]*sc[4]+sh[4]);
    a1.y = f2bf(in[5*S+p]*sc[5]+sh[5]);
    a1.z = f2bf(in[6*S+p]*sc[6]+sh[6]);
    a1.w = f2bf(in[7*S+p]*sc[7]+sh[7]);
    *(ushort4*)(outp + base + posA) = a0;
    *(ushort4*)(outp + base + posB) = a1;
  }
}

// ---------------- Q/K/V projection GEMMs (blocked frag loads) ----------------
__global__ __launch_bounds__(256) void qkv_gemm(unsigned short* __restrict__ ws,
    const float* __restrict__ bq, const float* __restrict__ bk, const float* __restrict__ bv)
{
  const int tid = threadIdx.x;
  const int lane = tid & 63, wave = tid >> 6;
  const int lq = lane & 15, lg = lane >> 4;
  const int lofs = lq*32 + lg*8;
  const int bid = blockIdx.x;
  const int inst = bid >> 6, tile = bid & 63;
  const int which = inst % 3, b = inst / 3;
  int mblk, nblk;
  if (which == 2) { mblk = tile & 31; nblk = tile >> 5; }
  else            { mblk = tile >> 5; nblk = tile & 31; }
  const int mbase = mblk*128 + (wave>>1)*64;
  const int nbase = nblk*128 + (wave&1)*64;

  const unsigned short* Amat;
  const unsigned short* Bmat;
  if (which == 0)      { Amat = ws + OFF_WQ;                   Bmat = ws + OFF_NY + (size_t)b*S*CC; }
  else if (which == 1) { Amat = ws + OFF_WK;                   Bmat = ws + OFF_NX + (size_t)b*S*CC; }
  else                 { Amat = ws + OFF_NX + (size_t)b*S*CC;  Bmat = ws + OFF_WV; }

  f32x4 acc[4][4];
  #pragma unroll
  for (int i = 0; i < 4; i++)
    #pragma unroll
    for (int j = 0; j < 4; j++)
      acc[i][j] = (f32x4){0.f,0.f,0.f,0.f};

  const unsigned short* Arow = Amat + (size_t)mbase*CC + lofs;
  const unsigned short* Brow = Bmat + (size_t)nbase*CC + lofs;

  for (int ks = 0; ks < CC; ks += 32) {
    bf16x8 af[4], bfr[4];
    #pragma unroll
    for (int mt = 0; mt < 4; mt++)
      af[mt] = *(const bf16x8*)(Arow + mt*16*CC + ks*16);
    #pragma unroll
    for (int nt = 0; nt < 4; nt++)
      bfr[nt] = *(const bf16x8*)(Brow + nt*16*CC + ks*16);
    #pragma unroll
    for (int mt = 0; mt < 4; mt++)
      #pragma unroll
      for (int nt = 0; nt < 4; nt++)
        acc[mt][nt] = MFMA16(af[mt], bfr[nt], acc[mt][nt]);
  }

  if (which < 2) {
    const float* bias = (which==0) ? bq : bk;
    const float scl = (which==0) ? 0.125f*1.44269504089f : 1.0f;
    unsigned short* Outp = ws + (which==0 ? OFF_Q : OFF_K) + (size_t)b*HH*S*DD;
    #pragma unroll
    for (int mt = 0; mt < 4; mt++){
      const int o = mbase + mt*16 + lg*4;
      const float4 bb = *(const float4*)(bias + o);
      const int hd = o >> 6, db = KI(o & 63);
      #pragma unroll
      for (int nt = 0; nt < 4; nt++){
        const int p = nbase + nt*16 + lq;
        f32x4 v = acc[mt][nt];
        ushort4 r;
        r.x = f2bf((v[0]+bb.x)*scl); r.y = f2bf((v[1]+bb.y)*scl);
        r.z = f2bf((v[2]+bb.z)*scl); r.w = f2bf((v[3]+bb.w)*scl);
        *(ushort4*)(Outp + ((size_t)hd*S + p)*DD + db) = r;
      }
    }
  } else {
    unsigned short* Outp = ws + OFF_V + (size_t)b*CC*S;
    #pragma unroll
    for (int nt = 0; nt < 4; nt++){
      const int o = nbase + nt*16 + lq;
      const float bb = bv[o];
      #pragma unroll
      for (int mt = 0; mt < 4; mt++){
        const int p = mbase + mt*16 + lg*4;
        f32x4 v = acc[mt][nt];
        ushort4 r;
        r.x = f2bf(v[0]+bb); r.y = f2bf(v[1]+bb);
        r.z = f2bf(v[2]+bb); r.w = f2bf(v[3]+bb);
        *(ushort4*)(Outp + (size_t)o*S + KI(p)) = r;
      }
    }
  }
}

// ---------------- flash attention v6: split-t + 32 q/wave ----------------
// grid 512: bid = (ch*32 + qblk)*8 + bh. Block: 4 waves x 32 q = 128 q over
// t-chunk of 2048. K/V LDS tiles [64][64] double-buffered (round-4 0-conflict
// layout), staged via global_load_lds w/ pre-XOR-swizzled source. 2 Q-frags
// per wave amortize K/V fragment reads. Defer-max online softmax, exp2 domain.
// Writes unnormalized partials (acc bf16, m/l f32); attn_merge combines.
__global__ __launch_bounds__(256, 2) void attn_k(unsigned short* __restrict__ ws)
{
  __shared__ __align__(1024) char lds[32768];   // K: 0/8192, V: 16384/24576
  const int tid = threadIdx.x;
  const int lane = tid & 63, wave = tid >> 6;
  const int lq = lane & 15, lg = lane >> 4;
  const int rsw = (lq & 7) << 4;
  const int bid = blockIdx.x;
  const int bh = bid & 7;
  const int rest = bid >> 3;                // 0..63
  const int qblk = rest & 31;
  const int ch = rest >> 5;                 // 0..1
  const int b = bh >> 2, h = bh & 3;
  const int tBeg = ch*2048, tEnd = tBeg + 2048;
  const unsigned short* Qp = ws + OFF_Q + (size_t)bh*S*DD;
  const unsigned short* Kp = ws + OFF_K + (size_t)bh*S*DD;
  const unsigned short* Vp = ws + OFF_V + ((size_t)b*CC + h*DD)*S;
  const int qbw = qblk*128 + wave*32;       // wave's 32 q

  bf16x8 qf[2][2];
  #pragma unroll
  for (int f = 0; f < 2; f++)
    #pragma unroll
    for (int hh = 0; hh < 2; hh++)
      qf[f][hh] = *(const bf16x8*)(Qp + (size_t)(qbw + f*16 + lq)*DD + hh*32 + lg*8);

  // staging lane constants (identical pattern for K and V tiles)
  const int csel = ((lane & 7) ^ ((lane >> 3) & 7)) * 8;  // pre-swizzled source chunk
  const int srow = wave*16 + (lane >> 3);                 // tile row (+j*8)
  // ds_read per-lane byte offsets
  const int kofs0 = lq*128 + ((lg*16) ^ rsw);
  const int kofs1 = kofs0 ^ 64;

  f32x4 acc[4][2];
  #pragma unroll
  for (int i = 0; i < 4; i++)
    #pragma unroll
    for (int f = 0; f < 2; f++)
      acc[i][f] = (f32x4){0.f,0.f,0.f,0.f};
  float mr[2] = {-1e30f, -1e30f};
  float lr[2] = {0.f, 0.f};

  // prologue: stage tile tBeg into buf0
  #pragma unroll
  for (int j = 0; j < 2; j++){
    const int row = srow + j*8;
    GLOAD_LDS16(Kp + (size_t)(tBeg + row)*DD + csel, lds + wave*2048 + j*1024);
    GLOAD_LDS16(Vp + (size_t)row*S + tBeg + csel,    lds + 16384 + wave*2048 + j*1024);
  }
  __syncthreads();

  int cur = 0;
  for (int t0 = tBeg; t0 < tEnd; t0 += 64){
    const char* kb = lds + cur*8192;
    const char* vb = lds + 16384 + cur*8192;
    if (t0 + 64 < tEnd){
      char* kn = lds + (cur^1)*8192;
      char* vn = lds + 16384 + (cur^1)*8192;
      #pragma unroll
      for (int j = 0; j < 2; j++){
        const int row = srow + j*8;
        GLOAD_LDS16(Kp + (size_t)(t0 + 64 + row)*DD + csel, kn + wave*2048 + j*1024);
        GLOAD_LDS16(Vp + (size_t)row*S + (t0 + 64) + csel,  vn + wave*2048 + j*1024);
      }
    }
    // K fragments + QK^T (K-frags reused across both q-frags)
    bf16x8 kf[4][2];
    #pragma unroll
    for (int mt = 0; mt < 4; mt++){
      kf[mt][0] = *(const bf16x8*)(kb + mt*2048 + kofs0);
      kf[mt][1] = *(const bf16x8*)(kb + mt*2048 + kofs1);
    }
    f32x4 st[2][4];
    #pragma unroll
    for (int f = 0; f < 2; f++)
      #pragma unroll
      for (int mt = 0; mt < 4; mt++){
        f32x4 z = (f32x4){0.f,0.f,0.f,0.f};
        z = MFMA16(kf[mt][0], qf[f][0], z);
        z = MFMA16(kf[mt][1], qf[f][1], z);
        st[f][mt] = z;
      }
    // V fragments (issued before softmax, consumed after)
    bf16x8 vf[4][2];
    #pragma unroll
    for (int dt = 0; dt < 4; dt++){
      vf[dt][0] = *(const bf16x8*)(vb + dt*2048 + kofs0);
      vf[dt][1] = *(const bf16x8*)(vb + dt*2048 + kofs1);
    }
    // online softmax (exp2 domain), combined defer-max THR=8
    float tmv[2];
    #pragma unroll
    for (int f = 0; f < 2; f++){
      float tm = fmaxf(
        fmaxf(fmaxf(fmaxf(st[f][0][0], st[f][0][1]), fmaxf(st[f][0][2], st[f][0][3])),
              fmaxf(fmaxf(st[f][1][0], st[f][1][1]), fmaxf(st[f][1][2], st[f][1][3]))),
        fmaxf(fmaxf(fmaxf(st[f][2][0], st[f][2][1]), fmaxf(st[f][2][2], st[f][2][3])),
              fmaxf(fmaxf(st[f][3][0], st[f][3][1]), fmaxf(st[f][3][2], st[f][3][3]))));
      tm = fmaxf(tm, __shfl_xor(tm, 16));
      tm = fmaxf(tm, __shfl_xor(tm, 32));
      tmv[f] = tm;
    }
    if (!__all((tmv[0] <= mr[0] + 8.f) && (tmv[1] <= mr[1] + 8.f))){
      #pragma unroll
      for (int f = 0; f < 2; f++){
        const float mnew = fmaxf(mr[f], tmv[f]);
        const float c = __builtin_amdgcn_exp2f(mr[f] - mnew);
        lr[f] *= c;
        #pragma unroll
        for (int dt = 0; dt < 4; dt++)
          #pragma unroll
          for (int r = 0; r < 4; r++)
            acc[dt][f][r] *= c;
        mr[f] = mnew;
      }
    }
    union PU { bf16x8 v; __bf16 e[8]; } p0[2], p1[2];
    #pragma unroll
    for (int f = 0; f < 2; f++){
      float ts = 0.f;
      #pragma unroll
      for (int mt = 0; mt < 4; mt++)
        #pragma unroll
        for (int r = 0; r < 4; r++){
          float e = __builtin_amdgcn_exp2f(st[f][mt][r] - mr[f]);
          ts += e;
          if (mt < 2) p0[f].e[mt*4+r] = (__bf16)e;
          else        p1[f].e[(mt-2)*4+r] = (__bf16)e;
        }
      ts += __shfl_xor(ts, 16);
      ts += __shfl_xor(ts, 32);
      lr[f] += ts;
    }
    // PV (V-frags reused across both q-frags)
    #pragma unroll
    for (int dt = 0; dt < 4; dt++)
      #pragma unroll
      for (int f = 0; f < 2; f++){
        f32x4 a = acc[dt][f];
        a = MFMA16(vf[dt][0], p0[f].v, a);
        a = MFMA16(vf[dt][1], p1[f].v, a);
        acc[dt][f] = a;
      }
    __syncthreads();
    cur ^= 1;
  }

  // epilogue: unnormalized partials
  unsigned short* PA = ws + OFF_PACC + (((size_t)ch*8 + bh)*S)*DD;
  float* ML = (float*)(ws + OFF_ML) + ((size_t)ch*8 + bh)*S*2;
  #pragma unroll
  for (int f = 0; f < 2; f++){
    const int q = qbw + f*16 + lq;
    #pragma unroll
    for (int dt = 0; dt < 4; dt++)
      *(ushort4*)(PA + (size_t)q*DD + dt*16 + lg*4) = pk4(acc[dt][f]);
    if (lg == 0){
      ML[(size_t)q*2]   = mr[f];
      ML[(size_t)q*2+1] = lr[f];
    }
  }
}

// ---------------- merge the 2 t-chunk partials ----------------
// grid 2048 (bh*256 + qg), 256 thr: 16 q x 16 d-quads.
__global__ __launch_bounds__(256) void attn_merge(unsigned short* __restrict__ ws)
{
  const int tid = threadIdx.x;
  const int bid = blockIdx.x;
  const int bh = bid >> 8, qg = bid & 255;
  const int b = bh >> 2, h = bh & 3;
  const int q = qg*16 + (tid >> 4);
  const int d = (tid & 15) * 4;
  const unsigned short* PA = ws + OFF_PACC;
  const float* ML = (const float*)(ws + OFF_ML);
  const size_t i0 = (size_t)bh*S + q;
  const size_t i1 = (size_t)(8 + bh)*S + q;
  const float m0 = ML[i0*2], l0 = ML[i0*2+1];
  const float m1 = ML[i1*2], l1 = ML[i1*2+1];
  const float M  = fmaxf(m0, m1);
  const float w0 = __builtin_amdgcn_exp2f(m0 - M);
  const float w1 = __builtin_amdgcn_exp2f(m1 - M);
  const float inv = 1.0f / (w0*l0 + w1*l1);
  const ushort4 a0 = *(const ushort4*)(PA + i0*DD + d);
  const ushort4 a1 = *(const ushort4*)(PA + i1*DD + d);
  f32x4 v;
  v[0] = (bf2f(a0.x)*w0 + bf2f(a1.x)*w1) * inv;
  v[1] = (bf2f(a0.y)*w0 + bf2f(a1.y)*w1) * inv;
  v[2] = (bf2f(a0.z)*w0 + bf2f(a1.z)*w1) * inv;
  v[3] = (bf2f(a0.w)*w0 + bf2f(a1.w)*w1) * inv;
  *(ushort4*)(ws + OFF_AO + (size_t)b*S*CC + BL256(q, h*64 + d)) = pk4(v);
}

// ---------------- output projection + residual (64x128 tiles, 256 blocks) ----------------
__global__ __launch_bounds__(256) void outproj_k(const unsigned short* __restrict__ ws,
    const float* __restrict__ bo, const float* __restrict__ x, float* __restrict__ out)
{
  const int tid = threadIdx.x;
  const int lane = tid & 63, wave = tid >> 6;
  const int lq = lane & 15, lg = lane >> 4;
  const int lofs = lq*32 + lg*8;
  const int bid = blockIdx.x;
  const int b = bid >> 7;
  const int tile = bid & 127;
  const int mtile = tile >> 1, ntile = tile & 1;
  const int mbase = mtile*64 + wave*16;
  const int nbase = ntile*128;
  const unsigned short* Amat = ws + OFF_AO + (size_t)b*S*CC;
  const unsigned short* Bmat = ws + OFF_WO;

  f32x4 acc[8];
  #pragma unroll
  for (int i = 0; i < 8; i++) acc[i] = (f32x4){0.f,0.f,0.f,0.f};

  const unsigned short* Arow = Amat + (size_t)mbase*CC + lofs;
  const unsigned short* Brow = Bmat + (size_t)nbase*CC + lofs;
  for (int ks = 0; ks < CC; ks += 32) {
    bf16x8 af = *(const bf16x8*)(Arow + ks*16);
    bf16x8 bfr[8];
    #pragma unroll
    for (int nt = 0; nt < 8; nt++)
      bfr[nt] = *(const bf16x8*)(Brow + nt*16*CC + ks*16);
    #pragma unroll
    for (int nt = 0; nt < 8; nt++)
      acc[nt] = MFMA16(af, bfr[nt], acc[nt]);
  }
  #pragma unroll
  for (int nt = 0; nt < 8; nt++){
    const int o = nbase + nt*16 + lq;
    const float bb = bo[o];
    const int p = mbase + lg*4;
    const size_t idx = ((size_t)b*CC + o)*S + p;
    const float4 xr = *(const float4*)(x + idx);
    f32x4 v = acc[nt];
    float4 r; r.x = v[0]+bb+xr.x; r.y = v[1]+bb+xr.y; r.z = v[2]+bb+xr.z; r.w = v[3]+bb+xr.w;
    *(float4*)(out + idx) = r;
  }
}

extern "C" void kernel_launch(void* const* d_in, const int* in_sizes, int n_in,
                              void* d_out, int out_size, void* d_ws, size_t ws_size,
                              hipStream_t stream) {
  const float* x  = (const float*)d_in[0];
  const float* y  = (const float*)d_in[1];
  const float* g1 = (const float*)d_in[2];
  const float* b1 = (const float*)d_in[3];
  const float* g2 = (const float*)d_in[4];
  const float* b2 = (const float*)d_in[5];
  const float* wq = (const float*)d_in[6];
  const float* bq = (const float*)d_in[7];
  const float* wk = (const float*)d_in[8];
  const float* bk = (const float*)d_in[9];
  const float* wv = (const float*)d_in[10];
  const float* bv = (const float*)d_in[11];
  const float* wo = (const float*)d_in[12];
  const float* bo = (const float*)d_in[13];
  float* out = (float*)d_out;
  unsigned short* ws16 = (unsigned short*)d_ws;

  convert_w  <<<256,  256, 0, stream>>>(wq, wk, wv, wo, ws16);
  groupnorm_k<<<128,  256, 0, stream>>>(x, y, g1, b1, g2, b2, ws16);
  qkv_gemm   <<<384,  256, 0, stream>>>(ws16, bq, bk, bv);
  attn_k     <<<512,  256, 0, stream>>>(ws16);
  attn_merge <<<2048, 256, 0, stream>>>(ws16);
  outproj_k  <<<256,  256, 0, stream>>>(ws16, bo, x, out);
}

// Round 7
// 111.069 us; speedup vs baseline: 4.9161x; 1.0637x over previous
//
#include <hip/hip_runtime.h>

typedef __bf16 bf16_t;
typedef bf16_t bf16x8 __attribute__((ext_vector_type(8)));
typedef float f32x4 __attribute__((ext_vector_type(4)));

#define MFMA16(a,b,c) __builtin_amdgcn_mfma_f32_16x16x32_bf16((a),(b),(c),0,0,0)

#define GLOAD_LDS16(gsrc, ldst) \
  __builtin_amdgcn_global_load_lds((const __attribute__((address_space(1))) unsigned int*)(gsrc), \
                                   (__attribute__((address_space(3))) unsigned int*)(ldst), 16, 0, 0)

__device__ __forceinline__ unsigned short f2bf(float f){
  unsigned int u = __builtin_bit_cast(unsigned int, f);
  u = (u + 0x7FFFu + ((u >> 16) & 1u)) >> 16;
  return (unsigned short)u;
}
__device__ __forceinline__ float bf2f(unsigned short u){
  return __builtin_bit_cast(float, (unsigned int)u << 16);
}
__device__ __forceinline__ ushort4 pk4(f32x4 v){
  union { __bf16 b[4]; ushort4 u; } r;
  r.b[0]=(__bf16)v[0]; r.b[1]=(__bf16)v[1]; r.b[2]=(__bf16)v[2]; r.b[3]=(__bf16)v[3];
  return r.u;
}

// KI: k-interleave within 64-elem segment (for Q/K/V consumed by attention).
__device__ __forceinline__ int KI(int d){   // d 4-aligned
  int gi = (d >> 2) & 15;
  int pos = (gi & 8) | ((gi & 3) << 1) | ((gi >> 2) & 1);
  return (d & ~63) | (pos << 2);
}

// Blocked fragment layout for GEMM operands [R][256]:
// wave fragment load at (rowbase*256 + ks*16 + lq*32 + lg*8) is contiguous 1KB.
__device__ __forceinline__ int BL256(int r, int c){
  return ((r >> 4) << 12) + (((c >> 5)) << 9) + ((r & 15) << 5)
       + (((c & 15) >> 2) << 3) + (((c >> 4) & 1) << 2) + (c & 3);
}

constexpr int BN = 2;
constexpr int CC = 256;
constexpr int S  = 4096;
constexpr int HH = 4;
constexpr int DD = 64;

constexpr size_t OFF_WQ = 0;
constexpr size_t OFF_WK = 65536;
constexpr size_t OFF_WV = 131072;
constexpr size_t OFF_WO = 196608;
constexpr size_t OFF_NY = 262144;                      // blocked [p][c]
constexpr size_t OFF_NX = OFF_NY + (size_t)BN*S*CC;    // blocked [p][c]
constexpr size_t OFF_Q  = OFF_NX + (size_t)BN*S*CC;    // [b][h][p][d~KI] (pre-scaled 0.125*log2e)
constexpr size_t OFF_K  = OFF_Q  + (size_t)BN*S*CC;    // [b][h][p][d~KI]
constexpr size_t OFF_V  = OFF_K  + (size_t)BN*S*CC;    // [b][c][p~KI]
constexpr size_t OFF_AO = OFF_V  + (size_t)BN*S*CC;    // (freed: reused as PACC ch2)
// Attention partials (3 t-chunks). Each chunk = 8*4096*64 = 2,097,152 ush -> exactly one region:
//   ch0 -> OFF_NY, ch1 -> OFF_NX, ch2 -> OFF_AO   (all dead after qkv_gemm)
// ML [3][8][4096][2] f32 overlays OFF_Q (clobbers Q[bh0..1.5]). SAFE because attn grid (768)
// is exactly co-resident (3 blocks/CU): every block reads Q in its prologue ~10^4 cycles
// before any epilogue ML write. qkv_gemm fully rewrites Q each call (deterministic).
__device__ __forceinline__ unsigned short* pacc_base(unsigned short* ws, int ch){
  return ws + (ch == 0 ? OFF_NY : (ch == 1 ? OFF_NX : OFF_AO));
}

// ---------------- fused weight-convert + GroupNorm ----------------
// blocks 0..127: groupnorm (x->NX, y->NY, blocked bf16). blocks 128..383: weight fp32->bf16 blocked.
__global__ __launch_bounds__(256) void prep_k(const float* __restrict__ x, const float* __restrict__ y,
    const float* __restrict__ g1, const float* __restrict__ b1,
    const float* __restrict__ g2, const float* __restrict__ b2,
    const float* __restrict__ wq, const float* __restrict__ wk,
    const float* __restrict__ wv, const float* __restrict__ wo,
    unsigned short* __restrict__ ws)
{
  __shared__ float red[8];
  __shared__ float mv[2];
  const int tid = threadIdx.x;
  const int bid = blockIdx.x;

  if (bid >= 128){
    const int idx = (bid - 128)*256 + tid;
    const int m = idx >> 14;
    const int off = (idx & 16383) << 2;
    const float* src = (m==0) ? wq : (m==1) ? wk : (m==2) ? wv : wo;
    float4 v = *(const float4*)(src + off);
    ushort4 r; r.x=f2bf(v.x); r.y=f2bf(v.y); r.z=f2bf(v.z); r.w=f2bf(v.w);
    const int o = off >> 8, c = off & 255;
    *(ushort4*)(ws + (size_t)m*65536 + BL256(o, c)) = r;
    return;
  }

  const int tsel = bid >> 6;
  const int rem  = bid & 63;
  const int b = rem >> 5, g = rem & 31;
  const float* in = (tsel ? y : x) + ((size_t)b*CC + g*8)*S;
  unsigned short* outp = ws + (tsel ? OFF_NY : OFF_NX) + (size_t)b*S*CC;
  const int j = g & 3;
  const int gk = (g >> 2) * 512;
  const int posA = (j & 1)*16 + (j >> 1)*4;
  const int posB = posA + 8;
  const float* gamma = (tsel ? g2 : g1) + g*8;
  const float* beta  = (tsel ? b2 : b1) + g*8;

  float s = 0.f, ss = 0.f;
  #pragma unroll
  for (int ci = 0; ci < 8; ci++){
    const float4* row = (const float4*)(in + (size_t)ci*S);
    #pragma unroll
    for (int i = 0; i < 4; i++){
      float4 v = row[tid + i*256];
      s  += v.x + v.y + v.z + v.w;
      ss += v.x*v.x + v.y*v.y + v.z*v.z + v.w*v.w;
    }
  }
  #pragma unroll
  for (int off = 1; off < 64; off <<= 1){
    s  += __shfl_xor(s,  off);
    ss += __shfl_xor(ss, off);
  }
  const int wave = tid >> 6, lane = tid & 63;
  if (lane == 0){ red[wave] = s; red[4+wave] = ss; }
  __syncthreads();
  if (tid == 0){
    float S1 = red[0]+red[1]+red[2]+red[3];
    float S2 = red[4]+red[5]+red[6]+red[7];
    const float invn = 1.0f/32768.0f;
    float mean = S1*invn;
    float var  = S2*invn - mean*mean;
    mv[0] = mean; mv[1] = rsqrtf(var + 1e-6f);
  }
  __syncthreads();
  const float mean = mv[0], rstd = mv[1];
  float sc[8], sh[8];
  #pragma unroll
  for (int ci = 0; ci < 8; ci++){ sc[ci] = rstd*gamma[ci]; sh[ci] = beta[ci] - mean*sc[ci]; }
  for (int i = 0; i < 16; i++){
    const int p = tid + i*256;
    const int base = ((p >> 4) << 12) + gk + ((p & 15) << 5);
    ushort4 a0, a1;
    a0.x = f2bf(in[0*S+p]*sc[0]+sh[0]);
    a0.y = f2bf(in[1*S+p]*sc[1]+sh[1]);
    a0.z = f2bf(in[2*S+p]*sc[2]+sh[2]);
    a0.w = f2bf(in[3*S+p]*sc[3]+sh[3]);
    a1.x = f2bf(in[4*S+p]*sc[4]+sh[4]);
    a1.y = f2bf(in[5*S+p]*sc[5]+sh[5]);
    a1.z = f2bf(in[6*S+p]*sc[6]+sh[6]);
    a1.w = f2bf(in[7*S+p]*sc[7]+sh[7]);
    *(ushort4*)(outp + base + posA) = a0;
    *(ushort4*)(outp + base + posB) = a1;
  }
}

// ---------------- Q/K/V projection GEMMs (blocked frag loads) ----------------
__global__ __launch_bounds__(256) void qkv_gemm(unsigned short* __restrict__ ws,
    const float* __restrict__ bq, const float* __restrict__ bk, const float* __restrict__ bv)
{
  const int tid = threadIdx.x;
  const int lane = tid & 63, wave = tid >> 6;
  const int lq = lane & 15, lg = lane >> 4;
  const int lofs = lq*32 + lg*8;
  const int bid = blockIdx.x;
  const int inst = bid >> 6, tile = bid & 63;
  const int which = inst % 3, b = inst / 3;
  int mblk, nblk;
  if (which == 2) { mblk = tile & 31; nblk = tile >> 5; }
  else            { mblk = tile >> 5; nblk = tile & 31; }
  const int mbase = mblk*128 + (wave>>1)*64;
  const int nbase = nblk*128 + (wave&1)*64;

  const unsigned short* Amat;
  const unsigned short* Bmat;
  if (which == 0)      { Amat = ws + OFF_WQ;                   Bmat = ws + OFF_NY + (size_t)b*S*CC; }
  else if (which == 1) { Amat = ws + OFF_WK;                   Bmat = ws + OFF_NX + (size_t)b*S*CC; }
  else                 { Amat = ws + OFF_NX + (size_t)b*S*CC;  Bmat = ws + OFF_WV; }

  f32x4 acc[4][4];
  #pragma unroll
  for (int i = 0; i < 4; i++)
    #pragma unroll
    for (int j = 0; j < 4; j++)
      acc[i][j] = (f32x4){0.f,0.f,0.f,0.f};

  const unsigned short* Arow = Amat + (size_t)mbase*CC + lofs;
  const unsigned short* Brow = Bmat + (size_t)nbase*CC + lofs;

  for (int ks = 0; ks < CC; ks += 32) {
    bf16x8 af[4], bfr[4];
    #pragma unroll
    for (int mt = 0; mt < 4; mt++)
      af[mt] = *(const bf16x8*)(Arow + mt*16*CC + ks*16);
    #pragma unroll
    for (int nt = 0; nt < 4; nt++)
      bfr[nt] = *(const bf16x8*)(Brow + nt*16*CC + ks*16);
    #pragma unroll
    for (int mt = 0; mt < 4; mt++)
      #pragma unroll
      for (int nt = 0; nt < 4; nt++)
        acc[mt][nt] = MFMA16(af[mt], bfr[nt], acc[mt][nt]);
  }

  if (which < 2) {
    const float* bias = (which==0) ? bq : bk;
    const float scl = (which==0) ? 0.125f*1.44269504089f : 1.0f;
    unsigned short* Outp = ws + (which==0 ? OFF_Q : OFF_K) + (size_t)b*HH*S*DD;
    #pragma unroll
    for (int mt = 0; mt < 4; mt++){
      const int o = mbase + mt*16 + lg*4;
      const float4 bb = *(const float4*)(bias + o);
      const int hd = o >> 6, db = KI(o & 63);
      #pragma unroll
      for (int nt = 0; nt < 4; nt++){
        const int p = nbase + nt*16 + lq;
        f32x4 v = acc[mt][nt];
        ushort4 r;
        r.x = f2bf((v[0]+bb.x)*scl); r.y = f2bf((v[1]+bb.y)*scl);
        r.z = f2bf((v[2]+bb.z)*scl); r.w = f2bf((v[3]+bb.w)*scl);
        *(ushort4*)(Outp + ((size_t)hd*S + p)*DD + db) = r;
      }
    }
  } else {
    unsigned short* Outp = ws + OFF_V + (size_t)b*CC*S;
    #pragma unroll
    for (int nt = 0; nt < 4; nt++){
      const int o = nbase + nt*16 + lq;
      const float bb = bv[o];
      #pragma unroll
      for (int mt = 0; mt < 4; mt++){
        const int p = mbase + mt*16 + lg*4;
        f32x4 v = acc[mt][nt];
        ushort4 r;
        r.x = f2bf(v[0]+bb); r.y = f2bf(v[1]+bb);
        r.z = f2bf(v[2]+bb); r.w = f2bf(v[3]+bb);
        *(ushort4*)(Outp + (size_t)o*S + KI(p)) = r;
      }
    }
  }
}

// ---------------- flash attention v7: 3-way split-t, 3 blocks/CU, MFMA l-sum ----------------
// grid 768: bid = ((ch*32 + qblk)*8) + bh. 4 waves x 32 q = 128 q per block.
// t-chunks: ch0=[0,1408) 22 steps, ch1=[1408,2752) 21, ch2=[2752,4096) 21.
// K/V LDS [64][64] double-buffered (0-conflict layout), global_load_lds staging.
// l accumulated via MFMA with all-ones A-operand (replaces VALU sum + shuffles).
__global__ __launch_bounds__(256, 3) void attn_k(unsigned short* __restrict__ ws)
{
  __shared__ __align__(1024) char lds[32768];   // K: 0/8192, V: 16384/24576
  const int tid = threadIdx.x;
  const int lane = tid & 63, wave = tid >> 6;
  const int lq = lane & 15, lg = lane >> 4;
  const int rsw = (lq & 7) << 4;
  const int bid = blockIdx.x;
  const int bh = bid & 7;
  const int rest = bid >> 3;                // 0..95
  const int qblk = rest & 31;
  const int ch = rest >> 5;                 // 0..2
  const int tBeg = ch*1344 + (ch ? 64 : 0);
  const int tEnd = tBeg + 1344 + (ch ? 0 : 64);
  const unsigned short* Qp = ws + OFF_Q + (size_t)bh*S*DD;
  const unsigned short* Kp = ws + OFF_K + (size_t)bh*S*DD;
  const int b = bh >> 2, h = bh & 3;
  const unsigned short* Vp = ws + OFF_V + ((size_t)b*CC + h*DD)*S;
  const int qbw = qblk*128 + wave*32;

  bf16x8 qf[2][2];
  #pragma unroll
  for (int f = 0; f < 2; f++)
    #pragma unroll
    for (int hh = 0; hh < 2; hh++)
      qf[f][hh] = *(const bf16x8*)(Qp + (size_t)(qbw + f*16 + lq)*DD + hh*32 + lg*8);

  bf16x8 ones;
  #pragma unroll
  for (int i = 0; i < 8; i++) ones[i] = (__bf16)1.0f;

  const int csel = ((lane & 7) ^ ((lane >> 3) & 7)) * 8;
  const int srow = wave*16 + (lane >> 3);
  const int kofs0 = lq*128 + ((lg*16) ^ rsw);
  const int kofs1 = kofs0 ^ 64;

  f32x4 acc[4][2];
  #pragma unroll
  for (int i = 0; i < 4; i++)
    #pragma unroll
    for (int f = 0; f < 2; f++)
      acc[i][f] = (f32x4){0.f,0.f,0.f,0.f};
  f32x4 accL[2] = {(f32x4){0.f,0.f,0.f,0.f}, (f32x4){0.f,0.f,0.f,0.f}};
  float mr[2] = {-1e30f, -1e30f};

  #pragma unroll
  for (int j = 0; j < 2; j++){
    const int row = srow + j*8;
    GLOAD_LDS16(Kp + (size_t)(tBeg + row)*DD + csel, lds + wave*2048 + j*1024);
    GLOAD_LDS16(Vp + (size_t)row*S + tBeg + csel,    lds + 16384 + wave*2048 + j*1024);
  }
  __syncthreads();

  int cur = 0;
  for (int t0 = tBeg; t0 < tEnd; t0 += 64){
    const char* kb = lds + cur*8192;
    const char* vb = lds + 16384 + cur*8192;
    if (t0 + 64 < tEnd){
      char* kn = lds + (cur^1)*8192;
      char* vn = lds + 16384 + (cur^1)*8192;
      #pragma unroll
      for (int j = 0; j < 2; j++){
        const int row = srow + j*8;
        GLOAD_LDS16(Kp + (size_t)(t0 + 64 + row)*DD + csel, kn + wave*2048 + j*1024);
        GLOAD_LDS16(Vp + (size_t)row*S + (t0 + 64) + csel,  vn + wave*2048 + j*1024);
      }
    }
    bf16x8 kf[4][2];
    #pragma unroll
    for (int mt = 0; mt < 4; mt++){
      kf[mt][0] = *(const bf16x8*)(kb + mt*2048 + kofs0);
      kf[mt][1] = *(const bf16x8*)(kb + mt*2048 + kofs1);
    }
    f32x4 st[2][4];
    #pragma unroll
    for (int f = 0; f < 2; f++)
      #pragma unroll
      for (int mt = 0; mt < 4; mt++){
        f32x4 z = (f32x4){0.f,0.f,0.f,0.f};
        z = MFMA16(kf[mt][0], qf[f][0], z);
        z = MFMA16(kf[mt][1], qf[f][1], z);
        st[f][mt] = z;
      }
    bf16x8 vf[4][2];
    #pragma unroll
    for (int dt = 0; dt < 4; dt++){
      vf[dt][0] = *(const bf16x8*)(vb + dt*2048 + kofs0);
      vf[dt][1] = *(const bf16x8*)(vb + dt*2048 + kofs1);
    }
    // online softmax (exp2 domain), combined defer-max THR=8
    float tmv[2];
    #pragma unroll
    for (int f = 0; f < 2; f++){
      float tm = fmaxf(
        fmaxf(fmaxf(fmaxf(st[f][0][0], st[f][0][1]), fmaxf(st[f][0][2], st[f][0][3])),
              fmaxf(fmaxf(st[f][1][0], st[f][1][1]), fmaxf(st[f][1][2], st[f][1][3]))),
        fmaxf(fmaxf(fmaxf(st[f][2][0], st[f][2][1]), fmaxf(st[f][2][2], st[f][2][3])),
              fmaxf(fmaxf(st[f][3][0], st[f][3][1]), fmaxf(st[f][3][2], st[f][3][3]))));
      tm = fmaxf(tm, __shfl_xor(tm, 16));
      tm = fmaxf(tm, __shfl_xor(tm, 32));
      tmv[f] = tm;
    }
    if (!__all((tmv[0] <= mr[0] + 8.f) && (tmv[1] <= mr[1] + 8.f))){
      #pragma unroll
      for (int f = 0; f < 2; f++){
        const float mnew = fmaxf(mr[f], tmv[f]);
        const float c = __builtin_amdgcn_exp2f(mr[f] - mnew);
        #pragma unroll
        for (int dt = 0; dt < 4; dt++)
          #pragma unroll
          for (int r = 0; r < 4; r++)
            acc[dt][f][r] *= c;
        #pragma unroll
        for (int r = 0; r < 4; r++) accL[f][r] *= c;
        mr[f] = mnew;
      }
    }
    union PU { bf16x8 v; __bf16 e[8]; } p0[2], p1[2];
    #pragma unroll
    for (int f = 0; f < 2; f++){
      #pragma unroll
      for (int mt = 0; mt < 4; mt++)
        #pragma unroll
        for (int r = 0; r < 4; r++){
          float e = __builtin_amdgcn_exp2f(st[f][mt][r] - mr[f]);
          if (mt < 2) p0[f].e[mt*4+r] = (__bf16)e;
          else        p1[f].e[(mt-2)*4+r] = (__bf16)e;
        }
    }
    // PV + l-sum (ones-A MFMA: every acc row = sum over t of P)
    #pragma unroll
    for (int dt = 0; dt < 4; dt++)
      #pragma unroll
      for (int f = 0; f < 2; f++){
        f32x4 a = acc[dt][f];
        a = MFMA16(vf[dt][0], p0[f].v, a);
        a = MFMA16(vf[dt][1], p1[f].v, a);
        acc[dt][f] = a;
      }
    #pragma unroll
    for (int f = 0; f < 2; f++){
      accL[f] = MFMA16(ones, p0[f].v, accL[f]);
      accL[f] = MFMA16(ones, p1[f].v, accL[f]);
    }
    __syncthreads();
    cur ^= 1;
  }

  // epilogue: unnormalized partials (PACC bf16) + m/l
  unsigned short* PA = pacc_base(ws, ch) + (size_t)bh*S*DD;
  float* ML = (float*)(ws + OFF_Q) + ((size_t)ch*8 + bh)*S*2;
  #pragma unroll
  for (int f = 0; f < 2; f++){
    const int q = qbw + f*16 + lq;
    #pragma unroll
    for (int dt = 0; dt < 4; dt++)
      *(ushort4*)(PA + (size_t)q*DD + dt*16 + lg*4) = pk4(acc[dt][f]);
    if (lg == 0){
      ML[(size_t)q*2]   = mr[f];
      ML[(size_t)q*2+1] = accL[f][0];
    }
  }
}

// ---------------- output projection: fused 3-chunk merge + GEMM + residual ----------------
// 256 blocks: (b, 64 p-rows, 128 o-cols). Merge partials -> LDS blocked A-tile -> MFMA.
__global__ __launch_bounds__(256) void outproj_k(unsigned short* __restrict__ ws,
    const float* __restrict__ bo, const float* __restrict__ x, float* __restrict__ out)
{
  __shared__ unsigned short ldsA[16384];    // 64 x 256 blocked, 32KB
  __shared__ float wtab[64][4][3];          // per (q_local, h): 3 chunk weights
  const int tid = threadIdx.x;
  const int lane = tid & 63, wave = tid >> 6;
  const int lq = lane & 15, lg = lane >> 4;
  const int lofs = lq*32 + lg*8;
  const int bid = blockIdx.x;
  const int b = bid >> 7;
  const int tile = bid & 127;
  const int mtile = tile >> 1, ntile = tile & 1;
  const int qg = mtile*64;                  // p-row base
  const int nbase = ntile*128;

  // phase 1: merge weights per (q,h)
  {
    const int q = tid >> 2, h = tid & 3;
    const float* MLb = (const float*)(ws + OFF_Q);
    float m[3], l[3];
    #pragma unroll
    for (int c = 0; c < 3; c++){
      const float* p = MLb + (((size_t)c*8 + b*4 + h)*S + (qg + q))*2;
      m[c] = p[0]; l[c] = p[1];
    }
    const float M = fmaxf(m[0], fmaxf(m[1], m[2]));
    const float w0 = __builtin_amdgcn_exp2f(m[0] - M);
    const float w1 = __builtin_amdgcn_exp2f(m[1] - M);
    const float w2 = __builtin_amdgcn_exp2f(m[2] - M);
    const float inv = 1.0f / (w0*l[0] + w1*l[1] + w2*l[2]);
    wtab[q][h][0] = w0*inv; wtab[q][h][1] = w1*inv; wtab[q][h][2] = w2*inv;
  }
  __syncthreads();

  // phase 2: merge 64q x 256c into blocked LDS A-tile
  #pragma unroll
  for (int it = 0; it < 16; it++){
    const int w = it*256 + tid;
    const int q = w >> 6, cq = w & 63;
    const int h = cq >> 4, d = (cq & 15)*4;
    const size_t po = ((size_t)(b*4 + h)*S + (qg + q))*DD + d;
    const ushort4 a0 = *(const ushort4*)(ws + OFF_NY + po);
    const ushort4 a1 = *(const ushort4*)(ws + OFF_NX + po);
    const ushort4 a2 = *(const ushort4*)(ws + OFF_AO + po);
    const float w0 = wtab[q][h][0], w1 = wtab[q][h][1], w2 = wtab[q][h][2];
    f32x4 v;
    v[0] = bf2f(a0.x)*w0 + bf2f(a1.x)*w1 + bf2f(a2.x)*w2;
    v[1] = bf2f(a0.y)*w0 + bf2f(a1.y)*w1 + bf2f(a2.y)*w2;
    v[2] = bf2f(a0.z)*w0 + bf2f(a1.z)*w1 + bf2f(a2.z)*w2;
    v[3] = bf2f(a0.w)*w0 + bf2f(a1.w)*w1 + bf2f(a2.w)*w2;
    *(ushort4*)(ldsA + BL256(q, cq*4)) = pk4(v);
  }
  __syncthreads();

  // phase 3: GEMM (A from LDS, B=WO from global) + bias + residual
  f32x4 acc[8];
  #pragma unroll
  for (int i = 0; i < 8; i++) acc[i] = (f32x4){0.f,0.f,0.f,0.f};
  const unsigned short* Arow = ldsA + wave*16*CC + lofs;
  const unsigned short* Brow = ws + OFF_WO + (size_t)nbase*CC + lofs;
  for (int ks = 0; ks < CC; ks += 32) {
    bf16x8 af = *(const bf16x8*)(Arow + ks*16);
    bf16x8 bfr[8];
    #pragma unroll
    for (int nt = 0; nt < 8; nt++)
      bfr[nt] = *(const bf16x8*)(Brow + nt*16*CC + ks*16);
    #pragma unroll
    for (int nt = 0; nt < 8; nt++)
      acc[nt] = MFMA16(af, bfr[nt], acc[nt]);
  }
  #pragma unroll
  for (int nt = 0; nt < 8; nt++){
    const int o = nbase + nt*16 + lq;
    const float bb = bo[o];
    const int p = qg + wave*16 + lg*4;
    const size_t idx = ((size_t)b*CC + o)*S + p;
    const float4 xr = *(const float4*)(x + idx);
    f32x4 v = acc[nt];
    float4 r; r.x = v[0]+bb+xr.x; r.y = v[1]+bb+xr.y; r.z = v[2]+bb+xr.z; r.w = v[3]+bb+xr.w;
    *(float4*)(out + idx) = r;
  }
}

extern "C" void kernel_launch(void* const* d_in, const int* in_sizes, int n_in,
                              void* d_out, int out_size, void* d_ws, size_t ws_size,
                              hipStream_t stream) {
  const float* x  = (const float*)d_in[0];
  const float* y  = (const float*)d_in[1];
  const float* g1 = (const float*)d_in[2];
  const float* b1 = (const float*)d_in[3];
  const float* g2 = (const float*)d_in[4];
  const float* b2 = (const float*)d_in[5];
  const float* wq = (const float*)d_in[6];
  const float* bq = (const float*)d_in[7];
  const float* wk = (const float*)d_in[8];
  const float* bk = (const float*)d_in[9];
  const float* wv = (const float*)d_in[10];
  const float* bv = (const float*)d_in[11];
  const float* wo = (const float*)d_in[12];
  const float* bo = (const float*)d_in[13];
  float* out = (float*)d_out;
  unsigned short* ws16 = (unsigned short*)d_ws;

  prep_k   <<<384, 256, 0, stream>>>(x, y, g1, b1, g2, b2, wq, wk, wv, wo, ws16);
  qkv_gemm <<<384, 256, 0, stream>>>(ws16, bq, bk, bv);
  attn_k   <<<768, 256, 0, stream>>>(ws16);
  outproj_k<<<256, 256, 0, stream>>>(ws16, bo, x, out);
}

// Round 8
// 108.545 us; speedup vs baseline: 5.0304x; 1.0233x over previous
//
#include <hip/hip_runtime.h>

typedef __bf16 bf16_t;
typedef bf16_t bf16x8 __attribute__((ext_vector_type(8)));
typedef float f32x4 __attribute__((ext_vector_type(4)));

#define MFMA16(a,b,c) __builtin_amdgcn_mfma_f32_16x16x32_bf16((a),(b),(c),0,0,0)

#define GLOAD_LDS16(gsrc, ldst) \
  __builtin_amdgcn_global_load_lds((const __attribute__((address_space(1))) unsigned int*)(gsrc), \
                                   (__attribute__((address_space(3))) unsigned int*)(ldst), 16, 0, 0)

__device__ __forceinline__ unsigned short f2bf(float f){
  unsigned int u = __builtin_bit_cast(unsigned int, f);
  u = (u + 0x7FFFu + ((u >> 16) & 1u)) >> 16;
  return (unsigned short)u;
}
__device__ __forceinline__ float bf2f(unsigned short u){
  return __builtin_bit_cast(float, (unsigned int)u << 16);
}
__device__ __forceinline__ ushort4 pk4(f32x4 v){
  union { __bf16 b[4]; ushort4 u; } r;
  r.b[0]=(__bf16)v[0]; r.b[1]=(__bf16)v[1]; r.b[2]=(__bf16)v[2]; r.b[3]=(__bf16)v[3];
  return r.u;
}

// KI: k-interleave within 64-elem segment (for Q/K/V consumed by attention).
__device__ __forceinline__ int KI(int d){   // d 4-aligned
  int gi = (d >> 2) & 15;
  int pos = (gi & 8) | ((gi & 3) << 1) | ((gi >> 2) & 1);
  return (d & ~63) | (pos << 2);
}

// Blocked fragment layout for GEMM operands [R][256]:
// wave fragment load at (rowbase*256 + ks*16 + lq*32 + lg*8) is contiguous 1KB.
__device__ __forceinline__ int BL256(int r, int c){
  return ((r >> 4) << 12) + (((c >> 5)) << 9) + ((r & 15) << 5)
       + (((c & 15) >> 2) << 3) + (((c >> 4) & 1) << 2) + (c & 3);
}

constexpr int BN = 2;
constexpr int CC = 256;
constexpr int S  = 4096;
constexpr int HH = 4;
constexpr int DD = 64;

constexpr size_t OFF_WQ = 0;
constexpr size_t OFF_WK = 65536;
constexpr size_t OFF_WV = 131072;
constexpr size_t OFF_WO = 196608;
constexpr size_t OFF_NY = 262144;                      // blocked [p][c]
constexpr size_t OFF_NX = OFF_NY + (size_t)BN*S*CC;    // blocked [p][c]
constexpr size_t OFF_Q  = OFF_NX + (size_t)BN*S*CC;    // [b][h][p][d~KI] (pre-scaled 0.125*log2e)
constexpr size_t OFF_K  = OFF_Q  + (size_t)BN*S*CC;    // [b][h][p][d~KI]
constexpr size_t OFF_V  = OFF_K  + (size_t)BN*S*CC;    // [b][c][p~KI]
constexpr size_t OFF_AO = OFF_V  + (size_t)BN*S*CC;    // (freed: reused as PACC ch2)
// Attention partials (3 t-chunks): ch0->NY, ch1->NX, ch2->AO (dead after qkv_gemm).
// ML [3][8][4096][2] f32 overlays OFF_Q (clobbers Q[bh0..1.5]). SAFE: attn grid (768)
// is exactly co-resident (3 blocks/CU); every block reads Q in its prologue before
// any epilogue ML write. qkv_gemm fully rewrites Q each call (deterministic).
__device__ __forceinline__ unsigned short* pacc_base(unsigned short* ws, int ch){
  return ws + (ch == 0 ? OFF_NY : (ch == 1 ? OFF_NX : OFF_AO));
}

// ---------------- fused weight-convert + GroupNorm ----------------
__global__ __launch_bounds__(256) void prep_k(const float* __restrict__ x, const float* __restrict__ y,
    const float* __restrict__ g1, const float* __restrict__ b1,
    const float* __restrict__ g2, const float* __restrict__ b2,
    const float* __restrict__ wq, const float* __restrict__ wk,
    const float* __restrict__ wv, const float* __restrict__ wo,
    unsigned short* __restrict__ ws)
{
  __shared__ float red[8];
  __shared__ float mv[2];
  const int tid = threadIdx.x;
  const int bid = blockIdx.x;

  if (bid >= 128){
    const int idx = (bid - 128)*256 + tid;
    const int m = idx >> 14;
    const int off = (idx & 16383) << 2;
    const float* src = (m==0) ? wq : (m==1) ? wk : (m==2) ? wv : wo;
    float4 v = *(const float4*)(src + off);
    ushort4 r; r.x=f2bf(v.x); r.y=f2bf(v.y); r.z=f2bf(v.z); r.w=f2bf(v.w);
    const int o = off >> 8, c = off & 255;
    *(ushort4*)(ws + (size_t)m*65536 + BL256(o, c)) = r;
    return;
  }

  const int tsel = bid >> 6;
  const int rem  = bid & 63;
  const int b = rem >> 5, g = rem & 31;
  const float* in = (tsel ? y : x) + ((size_t)b*CC + g*8)*S;
  unsigned short* outp = ws + (tsel ? OFF_NY : OFF_NX) + (size_t)b*S*CC;
  const int j = g & 3;
  const int gk = (g >> 2) * 512;
  const int posA = (j & 1)*16 + (j >> 1)*4;
  const int posB = posA + 8;
  const float* gamma = (tsel ? g2 : g1) + g*8;
  const float* beta  = (tsel ? b2 : b1) + g*8;

  float s = 0.f, ss = 0.f;
  #pragma unroll
  for (int ci = 0; ci < 8; ci++){
    const float4* row = (const float4*)(in + (size_t)ci*S);
    #pragma unroll
    for (int i = 0; i < 4; i++){
      float4 v = row[tid + i*256];
      s  += v.x + v.y + v.z + v.w;
      ss += v.x*v.x + v.y*v.y + v.z*v.z + v.w*v.w;
    }
  }
  #pragma unroll
  for (int off = 1; off < 64; off <<= 1){
    s  += __shfl_xor(s,  off);
    ss += __shfl_xor(ss, off);
  }
  const int wave = tid >> 6, lane = tid & 63;
  if (lane == 0){ red[wave] = s; red[4+wave] = ss; }
  __syncthreads();
  if (tid == 0){
    float S1 = red[0]+red[1]+red[2]+red[3];
    float S2 = red[4]+red[5]+red[6]+red[7];
    const float invn = 1.0f/32768.0f;
    float mean = S1*invn;
    float var  = S2*invn - mean*mean;
    mv[0] = mean; mv[1] = rsqrtf(var + 1e-6f);
  }
  __syncthreads();
  const float mean = mv[0], rstd = mv[1];
  float sc[8], sh[8];
  #pragma unroll
  for (int ci = 0; ci < 8; ci++){ sc[ci] = rstd*gamma[ci]; sh[ci] = beta[ci] - mean*sc[ci]; }
  for (int i = 0; i < 16; i++){
    const int p = tid + i*256;
    const int base = ((p >> 4) << 12) + gk + ((p & 15) << 5);
    ushort4 a0, a1;
    a0.x = f2bf(in[0*S+p]*sc[0]+sh[0]);
    a0.y = f2bf(in[1*S+p]*sc[1]+sh[1]);
    a0.z = f2bf(in[2*S+p]*sc[2]+sh[2]);
    a0.w = f2bf(in[3*S+p]*sc[3]+sh[3]);
    a1.x = f2bf(in[4*S+p]*sc[4]+sh[4]);
    a1.y = f2bf(in[5*S+p]*sc[5]+sh[5]);
    a1.z = f2bf(in[6*S+p]*sc[6]+sh[6]);
    a1.w = f2bf(in[7*S+p]*sc[7]+sh[7]);
    *(ushort4*)(outp + base + posA) = a0;
    *(ushort4*)(outp + base + posB) = a1;
  }
}

// ---------------- Q/K/V projection GEMMs, 768 blocks (3/CU) ----------------
// bid<512: Q/K. tile 64o x 128p, wave = 32o x 64p (acc[2][4]).
// bid>=512: V. tile 128p x 64o, wave = 64p x 32o (acc[4][2]).
__global__ __launch_bounds__(256, 3) void qkv_gemm(unsigned short* __restrict__ ws,
    const float* __restrict__ bq, const float* __restrict__ bk, const float* __restrict__ bv)
{
  const int tid = threadIdx.x;
  const int lane = tid & 63, wave = tid >> 6;
  const int lq = lane & 15, lg = lane >> 4;
  const int lofs = lq*32 + lg*8;
  const int bid = blockIdx.x;

  if (bid < 512){
    const int inst2 = bid >> 7;             // 0..3
    const int which = inst2 >> 1;           // 0=Q,1=K
    const int b = inst2 & 1;
    const int tile = bid & 127;
    const int mtile = tile & 3;             // 4 x 64 o-rows
    const int ntile = tile >> 2;            // 32 x 128 p-cols
    const int mbase = mtile*64 + (wave>>1)*32;
    const int nbase = ntile*128 + (wave&1)*64;
    const unsigned short* Amat = ws + (which==0 ? OFF_WQ : OFF_WK);
    const unsigned short* Bmat = ws + (which==0 ? OFF_NY : OFF_NX) + (size_t)b*S*CC;

    f32x4 acc[2][4];
    #pragma unroll
    for (int i = 0; i < 2; i++)
      #pragma unroll
      for (int j = 0; j < 4; j++)
        acc[i][j] = (f32x4){0.f,0.f,0.f,0.f};

    const unsigned short* Arow = Amat + (size_t)mbase*CC + lofs;
    const unsigned short* Brow = Bmat + (size_t)nbase*CC + lofs;
    for (int ks = 0; ks < CC; ks += 32) {
      bf16x8 af[2], bfr[4];
      #pragma unroll
      for (int mt = 0; mt < 2; mt++)
        af[mt] = *(const bf16x8*)(Arow + mt*16*CC + ks*16);
      #pragma unroll
      for (int nt = 0; nt < 4; nt++)
        bfr[nt] = *(const bf16x8*)(Brow + nt*16*CC + ks*16);
      #pragma unroll
      for (int mt = 0; mt < 2; mt++)
        #pragma unroll
        for (int nt = 0; nt < 4; nt++)
          acc[mt][nt] = MFMA16(af[mt], bfr[nt], acc[mt][nt]);
    }

    const float* bias = (which==0) ? bq : bk;
    const float scl = (which==0) ? 0.125f*1.44269504089f : 1.0f;
    unsigned short* Outp = ws + (which==0 ? OFF_Q : OFF_K) + (size_t)b*HH*S*DD;
    #pragma unroll
    for (int mt = 0; mt < 2; mt++){
      const int o = mbase + mt*16 + lg*4;
      const float4 bb = *(const float4*)(bias + o);
      const int hd = o >> 6, db = KI(o & 63);
      #pragma unroll
      for (int nt = 0; nt < 4; nt++){
        const int p = nbase + nt*16 + lq;
        f32x4 v = acc[mt][nt];
        ushort4 r;
        r.x = f2bf((v[0]+bb.x)*scl); r.y = f2bf((v[1]+bb.y)*scl);
        r.z = f2bf((v[2]+bb.z)*scl); r.w = f2bf((v[3]+bb.w)*scl);
        *(ushort4*)(Outp + ((size_t)hd*S + p)*DD + db) = r;
      }
    }
  } else {
    const int r0 = bid - 512;
    const int b = r0 >> 7;
    const int tile = r0 & 127;
    const int mtile = tile >> 2;            // 32 x 128 p-rows
    const int ntile = tile & 3;             // 4 x 64 o-cols
    const int mbase = mtile*128 + (wave>>1)*64;
    const int nbase = ntile*64 + (wave&1)*32;
    const unsigned short* Amat = ws + OFF_NX + (size_t)b*S*CC;
    const unsigned short* Bmat = ws + OFF_WV;

    f32x4 acc[4][2];
    #pragma unroll
    for (int i = 0; i < 4; i++)
      #pragma unroll
      for (int j = 0; j < 2; j++)
        acc[i][j] = (f32x4){0.f,0.f,0.f,0.f};

    const unsigned short* Arow = Amat + (size_t)mbase*CC + lofs;
    const unsigned short* Brow = Bmat + (size_t)nbase*CC + lofs;
    for (int ks = 0; ks < CC; ks += 32) {
      bf16x8 af[4], bfr[2];
      #pragma unroll
      for (int mt = 0; mt < 4; mt++)
        af[mt] = *(const bf16x8*)(Arow + mt*16*CC + ks*16);
      #pragma unroll
      for (int nt = 0; nt < 2; nt++)
        bfr[nt] = *(const bf16x8*)(Brow + nt*16*CC + ks*16);
      #pragma unroll
      for (int mt = 0; mt < 4; mt++)
        #pragma unroll
        for (int nt = 0; nt < 2; nt++)
          acc[mt][nt] = MFMA16(af[mt], bfr[nt], acc[mt][nt]);
    }

    unsigned short* Outp = ws + OFF_V + (size_t)b*CC*S;
    #pragma unroll
    for (int nt = 0; nt < 2; nt++){
      const int o = nbase + nt*16 + lq;
      const float bb = bv[o];
      #pragma unroll
      for (int mt = 0; mt < 4; mt++){
        const int p = mbase + mt*16 + lg*4;
        f32x4 v = acc[mt][nt];
        ushort4 r;
        r.x = f2bf(v[0]+bb); r.y = f2bf(v[1]+bb);
        r.z = f2bf(v[2]+bb); r.w = f2bf(v[3]+bb);
        *(ushort4*)(Outp + (size_t)o*S + KI(p)) = r;
      }
    }
  }
}

// ---------------- flash attention v8: 3-way split-t + setprio ----------------
__global__ __launch_bounds__(256, 3) void attn_k(unsigned short* __restrict__ ws)
{
  __shared__ __align__(1024) char lds[32768];   // K: 0/8192, V: 16384/24576
  const int tid = threadIdx.x;
  const int lane = tid & 63, wave = tid >> 6;
  const int lq = lane & 15, lg = lane >> 4;
  const int rsw = (lq & 7) << 4;
  const int bid = blockIdx.x;
  const int bh = bid & 7;
  const int rest = bid >> 3;                // 0..95
  const int qblk = rest & 31;
  const int ch = rest >> 5;                 // 0..2
  const int tBeg = ch*1344 + (ch ? 64 : 0);
  const int tEnd = tBeg + 1344 + (ch ? 0 : 64);
  const unsigned short* Qp = ws + OFF_Q + (size_t)bh*S*DD;
  const unsigned short* Kp = ws + OFF_K + (size_t)bh*S*DD;
  const int b = bh >> 2, h = bh & 3;
  const unsigned short* Vp = ws + OFF_V + ((size_t)b*CC + h*DD)*S;
  const int qbw = qblk*128 + wave*32;

  bf16x8 qf[2][2];
  #pragma unroll
  for (int f = 0; f < 2; f++)
    #pragma unroll
    for (int hh = 0; hh < 2; hh++)
      qf[f][hh] = *(const bf16x8*)(Qp + (size_t)(qbw + f*16 + lq)*DD + hh*32 + lg*8);

  bf16x8 ones;
  #pragma unroll
  for (int i = 0; i < 8; i++) ones[i] = (__bf16)1.0f;

  const int csel = ((lane & 7) ^ ((lane >> 3) & 7)) * 8;
  const int srow = wave*16 + (lane >> 3);
  const int kofs0 = lq*128 + ((lg*16) ^ rsw);
  const int kofs1 = kofs0 ^ 64;

  f32x4 acc[4][2];
  #pragma unroll
  for (int i = 0; i < 4; i++)
    #pragma unroll
    for (int f = 0; f < 2; f++)
      acc[i][f] = (f32x4){0.f,0.f,0.f,0.f};
  f32x4 accL[2] = {(f32x4){0.f,0.f,0.f,0.f}, (f32x4){0.f,0.f,0.f,0.f}};
  float mr[2] = {-1e30f, -1e30f};

  #pragma unroll
  for (int j = 0; j < 2; j++){
    const int row = srow + j*8;
    GLOAD_LDS16(Kp + (size_t)(tBeg + row)*DD + csel, lds + wave*2048 + j*1024);
    GLOAD_LDS16(Vp + (size_t)row*S + tBeg + csel,    lds + 16384 + wave*2048 + j*1024);
  }
  __syncthreads();

  int cur = 0;
  for (int t0 = tBeg; t0 < tEnd; t0 += 64){
    const char* kb = lds + cur*8192;
    const char* vb = lds + 16384 + cur*8192;
    if (t0 + 64 < tEnd){
      char* kn = lds + (cur^1)*8192;
      char* vn = lds + 16384 + (cur^1)*8192;
      #pragma unroll
      for (int j = 0; j < 2; j++){
        const int row = srow + j*8;
        GLOAD_LDS16(Kp + (size_t)(t0 + 64 + row)*DD + csel, kn + wave*2048 + j*1024);
        GLOAD_LDS16(Vp + (size_t)row*S + (t0 + 64) + csel,  vn + wave*2048 + j*1024);
      }
    }
    bf16x8 kf[4][2];
    #pragma unroll
    for (int mt = 0; mt < 4; mt++){
      kf[mt][0] = *(const bf16x8*)(kb + mt*2048 + kofs0);
      kf[mt][1] = *(const bf16x8*)(kb + mt*2048 + kofs1);
    }
    f32x4 st[2][4];
    __builtin_amdgcn_s_setprio(1);
    #pragma unroll
    for (int f = 0; f < 2; f++)
      #pragma unroll
      for (int mt = 0; mt < 4; mt++){
        f32x4 z = (f32x4){0.f,0.f,0.f,0.f};
        z = MFMA16(kf[mt][0], qf[f][0], z);
        z = MFMA16(kf[mt][1], qf[f][1], z);
        st[f][mt] = z;
      }
    __builtin_amdgcn_s_setprio(0);
    bf16x8 vf[4][2];
    #pragma unroll
    for (int dt = 0; dt < 4; dt++){
      vf[dt][0] = *(const bf16x8*)(vb + dt*2048 + kofs0);
      vf[dt][1] = *(const bf16x8*)(vb + dt*2048 + kofs1);
    }
    // online softmax (exp2 domain), combined defer-max THR=8
    float tmv[2];
    #pragma unroll
    for (int f = 0; f < 2; f++){
      float tm = fmaxf(
        fmaxf(fmaxf(fmaxf(st[f][0][0], st[f][0][1]), fmaxf(st[f][0][2], st[f][0][3])),
              fmaxf(fmaxf(st[f][1][0], st[f][1][1]), fmaxf(st[f][1][2], st[f][1][3]))),
        fmaxf(fmaxf(fmaxf(st[f][2][0], st[f][2][1]), fmaxf(st[f][2][2], st[f][2][3])),
              fmaxf(fmaxf(st[f][3][0], st[f][3][1]), fmaxf(st[f][3][2], st[f][3][3]))));
      tm = fmaxf(tm, __shfl_xor(tm, 16));
      tm = fmaxf(tm, __shfl_xor(tm, 32));
      tmv[f] = tm;
    }
    if (!__all((tmv[0] <= mr[0] + 8.f) && (tmv[1] <= mr[1] + 8.f))){
      #pragma unroll
      for (int f = 0; f < 2; f++){
        const float mnew = fmaxf(mr[f], tmv[f]);
        const float c = __builtin_amdgcn_exp2f(mr[f] - mnew);
        #pragma unroll
        for (int dt = 0; dt < 4; dt++)
          #pragma unroll
          for (int r = 0; r < 4; r++)
            acc[dt][f][r] *= c;
        #pragma unroll
        for (int r = 0; r < 4; r++) accL[f][r] *= c;
        mr[f] = mnew;
      }
    }
    union PU { bf16x8 v; __bf16 e[8]; } p0[2], p1[2];
    #pragma unroll
    for (int f = 0; f < 2; f++){
      #pragma unroll
      for (int mt = 0; mt < 4; mt++)
        #pragma unroll
        for (int r = 0; r < 4; r++){
          float e = __builtin_amdgcn_exp2f(st[f][mt][r] - mr[f]);
          if (mt < 2) p0[f].e[mt*4+r] = (__bf16)e;
          else        p1[f].e[(mt-2)*4+r] = (__bf16)e;
        }
    }
    // PV + l-sum (ones-A MFMA)
    __builtin_amdgcn_s_setprio(1);
    #pragma unroll
    for (int dt = 0; dt < 4; dt++)
      #pragma unroll
      for (int f = 0; f < 2; f++){
        f32x4 a = acc[dt][f];
        a = MFMA16(vf[dt][0], p0[f].v, a);
        a = MFMA16(vf[dt][1], p1[f].v, a);
        acc[dt][f] = a;
      }
    #pragma unroll
    for (int f = 0; f < 2; f++){
      accL[f] = MFMA16(ones, p0[f].v, accL[f]);
      accL[f] = MFMA16(ones, p1[f].v, accL[f]);
    }
    __builtin_amdgcn_s_setprio(0);
    __syncthreads();
    cur ^= 1;
  }

  // epilogue: unnormalized partials (PACC bf16) + m/l
  unsigned short* PA = pacc_base(ws, ch) + (size_t)bh*S*DD;
  float* ML = (float*)(ws + OFF_Q) + ((size_t)ch*8 + bh)*S*2;
  #pragma unroll
  for (int f = 0; f < 2; f++){
    const int q = qbw + f*16 + lq;
    #pragma unroll
    for (int dt = 0; dt < 4; dt++)
      *(ushort4*)(PA + (size_t)q*DD + dt*16 + lg*4) = pk4(acc[dt][f]);
    if (lg == 0){
      ML[(size_t)q*2]   = mr[f];
      ML[(size_t)q*2+1] = accL[f][0];
    }
  }
}

// ---------------- output projection: merge + GEMM + residual, 512 blocks (2/CU) ----------------
// tile 64q x 64o; wave = 32q x 32o.
__global__ __launch_bounds__(256, 2) void outproj_k(unsigned short* __restrict__ ws,
    const float* __restrict__ bo, const float* __restrict__ x, float* __restrict__ out)
{
  __shared__ unsigned short ldsA[16384];    // 64 x 256 blocked, 32KB
  __shared__ float wtab[64][4][3];
  const int tid = threadIdx.x;
  const int lane = tid & 63, wave = tid >> 6;
  const int lq = lane & 15, lg = lane >> 4;
  const int lofs = lq*32 + lg*8;
  const int bid = blockIdx.x;
  const int b = bid >> 8;
  const int r0 = bid & 255;
  const int mtile = r0 >> 2;                // 64 q-tiles of 64
  const int ntile = r0 & 3;                 // 4 o-tiles of 64
  const int qg = mtile*64;

  // phase 1: merge weights per (q,h)
  {
    const int q = tid >> 2, h = tid & 3;
    const float* MLb = (const float*)(ws + OFF_Q);
    float m[3], l[3];
    #pragma unroll
    for (int c = 0; c < 3; c++){
      const float* p = MLb + (((size_t)c*8 + b*4 + h)*S + (qg + q))*2;
      m[c] = p[0]; l[c] = p[1];
    }
    const float M = fmaxf(m[0], fmaxf(m[1], m[2]));
    const float w0 = __builtin_amdgcn_exp2f(m[0] - M);
    const float w1 = __builtin_amdgcn_exp2f(m[1] - M);
    const float w2 = __builtin_amdgcn_exp2f(m[2] - M);
    const float inv = 1.0f / (w0*l[0] + w1*l[1] + w2*l[2]);
    wtab[q][h][0] = w0*inv; wtab[q][h][1] = w1*inv; wtab[q][h][2] = w2*inv;
  }
  __syncthreads();

  // phase 2: merge 64q x 256c into blocked LDS A-tile
  #pragma unroll
  for (int it = 0; it < 16; it++){
    const int w = it*256 + tid;
    const int q = w >> 6, cq = w & 63;
    const int h = cq >> 4, d = (cq & 15)*4;
    const size_t po = ((size_t)(b*4 + h)*S + (qg + q))*DD + d;
    const ushort4 a0 = *(const ushort4*)(ws + OFF_NY + po);
    const ushort4 a1 = *(const ushort4*)(ws + OFF_NX + po);
    const ushort4 a2 = *(const ushort4*)(ws + OFF_AO + po);
    const float w0 = wtab[q][h][0], w1 = wtab[q][h][1], w2 = wtab[q][h][2];
    f32x4 v;
    v[0] = bf2f(a0.x)*w0 + bf2f(a1.x)*w1 + bf2f(a2.x)*w2;
    v[1] = bf2f(a0.y)*w0 + bf2f(a1.y)*w1 + bf2f(a2.y)*w2;
    v[2] = bf2f(a0.z)*w0 + bf2f(a1.z)*w1 + bf2f(a2.z)*w2;
    v[3] = bf2f(a0.w)*w0 + bf2f(a1.w)*w1 + bf2f(a2.w)*w2;
    *(ushort4*)(ldsA + BL256(q, cq*4)) = pk4(v);
  }
  __syncthreads();

  // phase 3: GEMM (A from LDS, B=WO from global) + bias + residual
  const int mbase = (wave>>1)*32;           // local q base
  const int nbase = ntile*64 + (wave&1)*32; // global o base
  f32x4 acc[2][2];
  #pragma unroll
  for (int i = 0; i < 2; i++)
    #pragma unroll
    for (int j = 0; j < 2; j++)
      acc[i][j] = (f32x4){0.f,0.f,0.f,0.f};
  const unsigned short* Arow = ldsA + (size_t)mbase*CC + lofs;
  const unsigned short* Brow = ws + OFF_WO + (size_t)nbase*CC + lofs;
  for (int ks = 0; ks < CC; ks += 32) {
    bf16x8 af[2], bfr[2];
    #pragma unroll
    for (int mt = 0; mt < 2; mt++)
      af[mt] = *(const bf16x8*)(Arow + mt*16*CC + ks*16);
    #pragma unroll
    for (int nt = 0; nt < 2; nt++)
      bfr[nt] = *(const bf16x8*)(Brow + nt*16*CC + ks*16);
    #pragma unroll
    for (int mt = 0; mt < 2; mt++)
      #pragma unroll
      for (int nt = 0; nt < 2; nt++)
        acc[mt][nt] = MFMA16(af[mt], bfr[nt], acc[mt][nt]);
  }
  #pragma unroll
  for (int nt = 0; nt < 2; nt++){
    const int o = nbase + nt*16 + lq;
    const float bb = bo[o];
    #pragma unroll
    for (int mt = 0; mt < 2; mt++){
      const int p = qg + mbase + mt*16 + lg*4;
      const size_t idx = ((size_t)b*CC + o)*S + p;
      const float4 xr = *(const float4*)(x + idx);
      f32x4 v = acc[mt][nt];
      float4 r; r.x = v[0]+bb+xr.x; r.y = v[1]+bb+xr.y; r.z = v[2]+bb+xr.z; r.w = v[3]+bb+xr.w;
      *(float4*)(out + idx) = r;
    }
  }
}

extern "C" void kernel_launch(void* const* d_in, const int* in_sizes, int n_in,
                              void* d_out, int out_size, void* d_ws, size_t ws_size,
                              hipStream_t stream) {
  const float* x  = (const float*)d_in[0];
  const float* y  = (const float*)d_in[1];
  const float* g1 = (const float*)d_in[2];
  const float* b1 = (const float*)d_in[3];
  const float* g2 = (const float*)d_in[4];
  const float* b2 = (const float*)d_in[5];
  const float* wq = (const float*)d_in[6];
  const float* bq = (const float*)d_in[7];
  const float* wk = (const float*)d_in[8];
  const float* bk = (const float*)d_in[9];
  const float* wv = (const float*)d_in[10];
  const float* bv = (const float*)d_in[11];
  const float* wo = (const float*)d_in[12];
  const float* bo = (const float*)d_in[13];
  float* out = (float*)d_out;
  unsigned short* ws16 = (unsigned short*)d_ws;

  prep_k   <<<384, 256, 0, stream>>>(x, y, g1, b1, g2, b2, wq, wk, wv, wo, ws16);
  qkv_gemm <<<768, 256, 0, stream>>>(ws16, bq, bk, bv);
  attn_k   <<<768, 256, 0, stream>>>(ws16);
  outproj_k<<<512, 256, 0, stream>>>(ws16, bo, x, out);
}